// Round 4
// baseline (1051.711 us; speedup 1.0000x reference)
//
#include <hip/hip_runtime.h>

// ---------------- problem constants ----------------
// B=8, T=32, S=256, DV=1024, NH=16, dh=64, DA=512, L2=2048
// video_x: [8, 8192, 1024] f32   audio_x: [8, 2048, 512] f32
// out: [8, 32, 2048] f32
//
// Pipeline (all f32):
//  qf = probe@wqT+bq ; qwt[d][h] = (1/8)*sum_{e in h} qf[e]*wk[e][d] ; qbs[h]
//  k1: per (b,t): score[s][h] = x[s,:].qwt[:,h]+qbs[h]; p=exp(score); ctxx[h][d]=sum_s p*x / l[h]
//  G1: ctx_part = ctxx(head-block) @ wv^T        (K-split 2 -> ctxp)
//  G2: pool_part = (ctxp0+ctxp1+bv) @ wo^T       (K-split 2 -> poolp)
//  LN: lno = LN(poolp0+poolp1+bo)
//  G3: vt_part = lno @ pw^T                      (K-split 2 -> vtp)
//  sim: (norm(vtp0+vtp1+pb) . norm(audio)) * exp(ls) + lb

// ws layout (float offsets)
#define OFF_QWT   0u                       // [1024][16]
#define OFF_QB    16384u                   // [16]
#define OFF_QF    16400u                   // [1024]
#define OFF_CTXX  18432u                   // [256][16][1024] = 4194304
#define OFF_CTXP  4212736u                 // [2][256][1024] = 524288
#define OFF_POOLP 4737024u                 // [2][256][1024] = 524288
#define OFF_LNO   5261312u                 // [256][1024]    = 262144
#define OFF_VTP   5523456u                 // [2][256][512]  = 262144
#define WS_FLOATS 5785600u                 // 23.1 MB

// ---------------- K0a: q_flat[e] = probe . wq[e,:] + bq[e] ----------------
__global__ __launch_bounds__(256) void k_qflat(const float* __restrict__ probe,
                                               const float* __restrict__ wq,
                                               const float* __restrict__ bq,
                                               float* __restrict__ qf) {
    int e = blockIdx.x, tid = threadIdx.x;
    const float* wr = wq + (size_t)e * 1024;
    float s = 0.f;
    for (int k = tid; k < 1024; k += 256) s += probe[k] * wr[k];
    s += __shfl_xor(s, 1);  s += __shfl_xor(s, 2);  s += __shfl_xor(s, 4);
    s += __shfl_xor(s, 8);  s += __shfl_xor(s, 16); s += __shfl_xor(s, 32);
    __shared__ float sm[4];
    if ((tid & 63) == 0) sm[tid >> 6] = s;
    __syncthreads();
    if (tid == 0) qf[e] = sm[0] + sm[1] + sm[2] + sm[3] + bq[e];
}

// ---------------- K0b: qwt[d][h] = (1/8) * sum_{e in h} qf[e]*wk[e][d] ----------------
__global__ __launch_bounds__(64) void k_qwt(const float* __restrict__ qf,
                                            const float* __restrict__ wk,
                                            const float* __restrict__ bk,
                                            float* __restrict__ qwt,
                                            float* __restrict__ qbs) {
    int kc = blockIdx.x, h = blockIdx.y, tid = threadIdx.x; // 64 threads = 1 wave
    int d = kc * 64 + tid;
    float s = 0.f;
    for (int e0 = 0; e0 < 64; ++e0) {
        int e = h * 64 + e0;
        s += qf[e] * wk[(size_t)e * 1024 + d];
    }
    qwt[d * 16 + h] = s * 0.125f;
    if (kc == 0) {
        float p = qf[h * 64 + tid] * bk[h * 64 + tid];
        p += __shfl_xor(p, 1);  p += __shfl_xor(p, 2);  p += __shfl_xor(p, 4);
        p += __shfl_xor(p, 8);  p += __shfl_xor(p, 16); p += __shfl_xor(p, 32);
        if (tid == 0) qbs[h] = p * 0.125f;
    }
}

// ---------------- K1: fused scores + softmax + ctxx ----------------
// 1024 threads (16 waves, 4/SIMD), one (b,t) per block, 16-row chunks,
// double-buffered LDS, register-staged prefetch.
// Phase A: wave w -> rows (w>>3)*8..+7, heads {w&7, (w&7)+8}; reduce width 64,
//          both heads share each x-read (16 floats/thread/row).
// Phase C: thread = (head-octet hq, row-half rh, f4-col c4); row-halves
//          combined once at the end through LDS scratch.
__global__ __launch_bounds__(1024, 4) void k1_attn(const float* __restrict__ x,
                                                   const float* __restrict__ qwt,
                                                   const float* __restrict__ qbs,
                                                   float* __restrict__ ctxx) {
    __shared__ __align__(16) float xs[2][16][1024];   // 128 KB
    __shared__ __align__(16) float p_lds[16][16];
    __shared__ float l_parts[2][16];
    __shared__ float linv_lds[16];

    const int tid  = threadIdx.x;
    const int lane = tid & 63;
    const int w    = tid >> 6;          // wave 0..15
    const int g    = w >> 3;            // phase-A row group (rows g*8..+7)
    const int hA   = w & 7;             // heads hA, hA+8
    const int hq   = tid >> 9;          // 0/1 : heads hq*8..+7 (phase C)
    const int rh   = (tid >> 8) & 1;    // row half (phase C rows rh*8..+7)
    const int c4   = tid & 255;         // float4 column (phase C)
    const int bt   = blockIdx.x;
    const float* xb = x + (size_t)bt * 262144;

    // per-thread query weights: d = lane*4 + 256*j + i
    float qwA[16], qwB[16];
#pragma unroll
    for (int j = 0; j < 4; ++j)
#pragma unroll
        for (int i = 0; i < 4; ++i) {
            int d = (lane << 2) + (j << 8) + i;
            qwA[j * 4 + i] = qwt[d * 16 + hA];
            qwB[j * 4 + i] = qwt[d * 16 + hA + 8];
        }
    const float qbA = qbs[hA], qbB = qbs[hA + 8];

    float4 acc[8];
#pragma unroll
    for (int hh = 0; hh < 8; ++hh) acc[hh] = make_float4(0.f, 0.f, 0.f, 0.f);
    float l_reg = 0.f;

    // prologue: chunk 0 into registers (coalesced float4)
    float4 st[4];
#pragma unroll
    for (int i = 0; i < 4; ++i)
        st[i] = *(const float4*)(xb + (size_t)(tid + i * 1024) * 4);

    for (int c = 0; c < 16; ++c) {
        const int cur = c & 1;
        float4* xw = (float4*)&xs[cur][0][0];
#pragma unroll
        for (int i = 0; i < 4; ++i) xw[tid + i * 1024] = st[i];
        __syncthreads();                  // chunk staged for all waves
        if (c < 15) {                     // prefetch next chunk during compute
            const float* nb = xb + (size_t)(c + 1) * 16384;
#pragma unroll
            for (int i = 0; i < 4; ++i)
                st[i] = *(const float4*)(nb + (size_t)(tid + i * 1024) * 4);
        }
        // ---- phase A: 8 rows, 2 heads sharing x-reads ----
#pragma unroll
        for (int rr = 0; rr < 8; ++rr) {
            const int r = g * 8 + rr;
            const float* xr = &xs[cur][r][0];
            float sA = 0.f, sB = 0.f;
#pragma unroll
            for (int j = 0; j < 4; ++j) {
                float4 a = *(const float4*)&xr[(lane << 2) + (j << 8)];
                sA += a.x * qwA[j * 4 + 0] + a.y * qwA[j * 4 + 1] + a.z * qwA[j * 4 + 2] + a.w * qwA[j * 4 + 3];
                sB += a.x * qwB[j * 4 + 0] + a.y * qwB[j * 4 + 1] + a.z * qwB[j * 4 + 2] + a.w * qwB[j * 4 + 3];
            }
            sA += __shfl_xor(sA, 1);  sB += __shfl_xor(sB, 1);
            sA += __shfl_xor(sA, 2);  sB += __shfl_xor(sB, 2);
            sA += __shfl_xor(sA, 4);  sB += __shfl_xor(sB, 4);
            sA += __shfl_xor(sA, 8);  sB += __shfl_xor(sB, 8);
            sA += __shfl_xor(sA, 16); sB += __shfl_xor(sB, 16);
            // cross-half combine: half0 ends with full head-A sum, half1 with head-B
            float v = (lane < 32) ? sB : sA;
            v = __shfl_xor(v, 32);
            float sTot = ((lane < 32) ? sA : sB) + v;
            // scores ~|0.05| -> exp with shift 0 is numerically safe here
            float pv = __expf(sTot + ((lane < 32) ? qbA : qbB));
            if (lane == 0)  { p_lds[r][hA] = pv;     l_reg += pv; }
            if (lane == 32) { p_lds[r][hA + 8] = pv; l_reg += pv; }
        }
        __syncthreads();                  // p_lds ready
        // ---- phase C: 8 rows (this row-half), 8 heads per thread ----
#pragma unroll
        for (int rr = 0; rr < 8; ++rr) {
            const int r = rh * 8 + rr;
            float4 xv = *(const float4*)&xs[cur][r][c4 * 4];
            float4 pa  = *(const float4*)&p_lds[r][hq * 8];
            float4 pb4 = *(const float4*)&p_lds[r][hq * 8 + 4];
            acc[0].x += pa.x * xv.x; acc[0].y += pa.x * xv.y; acc[0].z += pa.x * xv.z; acc[0].w += pa.x * xv.w;
            acc[1].x += pa.y * xv.x; acc[1].y += pa.y * xv.y; acc[1].z += pa.y * xv.z; acc[1].w += pa.y * xv.w;
            acc[2].x += pa.z * xv.x; acc[2].y += pa.z * xv.y; acc[2].z += pa.z * xv.z; acc[2].w += pa.z * xv.w;
            acc[3].x += pa.w * xv.x; acc[3].y += pa.w * xv.y; acc[3].z += pa.w * xv.z; acc[3].w += pa.w * xv.w;
            acc[4].x += pb4.x * xv.x; acc[4].y += pb4.x * xv.y; acc[4].z += pb4.x * xv.z; acc[4].w += pb4.x * xv.w;
            acc[5].x += pb4.y * xv.x; acc[5].y += pb4.y * xv.y; acc[5].z += pb4.y * xv.z; acc[5].w += pb4.y * xv.w;
            acc[6].x += pb4.z * xv.x; acc[6].y += pb4.z * xv.y; acc[6].z += pb4.z * xv.z; acc[6].w += pb4.z * xv.w;
            acc[7].x += pb4.w * xv.x; acc[7].y += pb4.w * xv.y; acc[7].z += pb4.w * xv.z; acc[7].w += pb4.w * xv.w;
        }
    }

    // l partials and row-half scratch exchange
    if (lane == 0)  l_parts[g][hA] = l_reg;
    if (lane == 32) l_parts[g][hA + 8] = l_reg;
    float4* scr = (float4*)&xs[0][0][0];
    const int slot = hq * 256 + c4;
    if (rh == 1) {
#pragma unroll
        for (int hh = 0; hh < 8; ++hh) scr[slot * 8 + hh] = acc[hh];
    }
    __syncthreads();
    if (tid < 16) linv_lds[tid] = 1.0f / (l_parts[0][tid] + l_parts[1][tid]);
    __syncthreads();
    if (rh == 0) {
        float* ob = ctxx + (size_t)bt * 16384;
#pragma unroll
        for (int hh = 0; hh < 8; ++hh) {
            float4 o = acc[hh];
            float4 o2 = scr[slot * 8 + hh];
            float li = linv_lds[hq * 8 + hh];
            o.x = (o.x + o2.x) * li; o.y = (o.y + o2.y) * li;
            o.z = (o.z + o2.z) * li; o.w = (o.w + o2.w) * li;
            *(float4*)(ob + (hq * 8 + hh) * 1024 + c4 * 4) = o;
        }
    }
}

// ---------------- K-split GEMM: outp[ks][r][e] = A_row(r)[koff:+512] . B[e, koff:+512] ----
// tile 16 rows x 64 cols, 256 threads, K-slice 512 (8 kc-steps of 64).
// FOLD=1: A_eff = A0 + A1 + biask (partial-combine folded into the load).
template<int FOLD>
__global__ __launch_bounds__(256, 2) void k_gemm2(const float* __restrict__ A0,
                                                  const float* __restrict__ A1,
                                                  const float* __restrict__ biask,
                                                  const float* __restrict__ Bw,
                                                  float* __restrict__ outp,
                                                  unsigned a_rstride, unsigned a_cstride,
                                                  unsigned ostride) {
    __shared__ __align__(16) float a_s[16][68];
    __shared__ __align__(16) float b_s[64][68];   // col-f4 swizzled: cs=(k4+e/4)&15
    const int tid = threadIdx.x;
    const int rc = blockIdx.x;     // row-chunk (16 rows)
    const int cb = blockIdx.y;     // col-block (64 cols)
    const int ks = blockIdx.z;     // K-split 0,1
    const int koff = ks * 512;
    const int rr = tid >> 4;       // output row 0..15
    const int ee = tid & 15;       // output cols ee*4..+3

    const size_t abase = (size_t)(rc * 16 + rr) * a_rstride + (size_t)cb * a_cstride + koff;

    float ac0 = 0.f, ac1 = 0.f, ac2 = 0.f, ac3 = 0.f;

    for (int kc = 0; kc < 8; ++kc) {
        __syncthreads();
        {   // stage A: 1 float4/thread
            float4 av = *(const float4*)(A0 + abase + kc * 64 + ee * 4);
            if (FOLD) {
                float4 a1 = *(const float4*)(A1 + abase + kc * 64 + ee * 4);
                float4 bk4 = *(const float4*)(biask + koff + kc * 64 + ee * 4);
                av.x += a1.x + bk4.x; av.y += a1.y + bk4.y;
                av.z += a1.z + bk4.z; av.w += a1.w + bk4.w;
            }
            *(float4*)&a_s[rr][ee * 4] = av;
        }
        // stage B: 4 float4/thread, linear global -> swizzled LDS
#pragma unroll
        for (int i = 0; i < 4; ++i) {
            int f4i = tid + i * 256;
            int e = f4i >> 4, k4 = f4i & 15;
            float4 bv4 = *(const float4*)(Bw + (size_t)(cb * 64 + e) * 1024 + koff + kc * 64 + k4 * 4);
            int cs = (k4 + (e >> 2)) & 15;
            *(float4*)&b_s[e][cs * 4] = bv4;
        }
        __syncthreads();
#pragma unroll
        for (int k4 = 0; k4 < 16; ++k4) {
            float4 av = *(const float4*)&a_s[rr][k4 * 4];
            int cs = (k4 + ee) & 15;
            float4 b0 = *(const float4*)&b_s[ee * 4 + 0][cs * 4];
            float4 b1 = *(const float4*)&b_s[ee * 4 + 1][cs * 4];
            float4 b2 = *(const float4*)&b_s[ee * 4 + 2][cs * 4];
            float4 b3 = *(const float4*)&b_s[ee * 4 + 3][cs * 4];
            ac0 += av.x * b0.x + av.y * b0.y + av.z * b0.z + av.w * b0.w;
            ac1 += av.x * b1.x + av.y * b1.y + av.z * b1.z + av.w * b1.w;
            ac2 += av.x * b2.x + av.y * b2.y + av.z * b2.z + av.w * b2.w;
            ac3 += av.x * b3.x + av.y * b3.y + av.z * b3.z + av.w * b3.w;
        }
    }
    float4 o = make_float4(ac0, ac1, ac2, ac3);
    *(float4*)(outp + (size_t)ks * 256 * ostride + (size_t)(rc * 16 + rr) * ostride + cb * 64 + ee * 4) = o;
}

// ---------------- LayerNorm over D=1024, folds poolp0+poolp1+bo ----------------
__global__ __launch_bounds__(256) void k_ln(const float* __restrict__ poolp,
                                            const float* __restrict__ bo,
                                            const float* __restrict__ g,
                                            const float* __restrict__ bb,
                                            float* __restrict__ out) {
    __shared__ float sm[8];
    int row = blockIdx.x, tid = threadIdx.x;
    float4 v0 = *(const float4*)(poolp + (size_t)row * 1024 + tid * 4);
    float4 v1 = *(const float4*)(poolp + 262144u + (size_t)row * 1024 + tid * 4);
    float4 bv = *(const float4*)(bo + tid * 4);
    float4 v;
    v.x = v0.x + v1.x + bv.x; v.y = v0.y + v1.y + bv.y;
    v.z = v0.z + v1.z + bv.z; v.w = v0.w + v1.w + bv.w;
    float s = v.x + v.y + v.z + v.w;
    float q = v.x * v.x + v.y * v.y + v.z * v.z + v.w * v.w;
    s += __shfl_xor(s, 1);  q += __shfl_xor(q, 1);
    s += __shfl_xor(s, 2);  q += __shfl_xor(q, 2);
    s += __shfl_xor(s, 4);  q += __shfl_xor(q, 4);
    s += __shfl_xor(s, 8);  q += __shfl_xor(q, 8);
    s += __shfl_xor(s, 16); q += __shfl_xor(q, 16);
    s += __shfl_xor(s, 32); q += __shfl_xor(q, 32);
    if ((tid & 63) == 0) { sm[tid >> 6] = s; sm[4 + (tid >> 6)] = q; }
    __syncthreads();
    float S = sm[0] + sm[1] + sm[2] + sm[3];
    float Q = sm[4] + sm[5] + sm[6] + sm[7];
    float mu = S * (1.f / 1024.f);
    float var = Q * (1.f / 1024.f) - mu * mu;
    float rs = rsqrtf(var + 1e-6f);
    float4 gg = *(const float4*)(g + tid * 4);
    float4 be = *(const float4*)(bb + tid * 4);
    float4 o;
    o.x = (v.x - mu) * rs * gg.x + be.x;
    o.y = (v.y - mu) * rs * gg.y + be.y;
    o.z = (v.z - mu) * rs * gg.z + be.z;
    o.w = (v.w - mu) * rs * gg.w + be.w;
    *(float4*)(out + (size_t)row * 1024 + tid * 4) = o;
}

// ---------------- sim = (vt_hat . a_hat) * exp(ls) + lb ----------------
// folds vtp0+vtp1+pb; block: 32 vt rows x 64 audio rows; grid (32,8)
__global__ __launch_bounds__(256, 2) void k_sim(const float* __restrict__ vtp,
                                                const float* __restrict__ pb,
                                                const float* __restrict__ audio,
                                                const float* __restrict__ ls,
                                                const float* __restrict__ lb,
                                                float* __restrict__ out) {
    __shared__ float a_s[64][65];
    __shared__ float v_s[32][65];
    __shared__ float rinv_a[64];
    __shared__ float rinv_v[32];
    const int tid = threadIdx.x;
    const int lc = blockIdx.x;   // 0..31
    const int b  = blockIdx.y;   // 0..7
    const int al = tid >> 2, ak = (tid & 3) * 16;
    const int vl = tid >> 3, vk = (tid & 7) * 8;
    const int rg = tid >> 4, lg = tid & 15;
    float ssa = 0.f, ssv = 0.f;
    float c00=0,c01=0,c02=0,c03=0,c10=0,c11=0,c12=0,c13=0;

    for (int kc = 0; kc < 8; ++kc) {
        __syncthreads();
        {
            const float* ap = audio + (size_t)b * 1048576 + (size_t)(lc * 64 + al) * 512 + kc * 64 + ak;
#pragma unroll
            for (int i = 0; i < 4; ++i) {
                float4 wv4 = *(const float4*)(ap + i * 4);
                ssa += wv4.x * wv4.x + wv4.y * wv4.y + wv4.z * wv4.z + wv4.w * wv4.w;
                a_s[al][ak + i * 4 + 0] = wv4.x; a_s[al][ak + i * 4 + 1] = wv4.y;
                a_s[al][ak + i * 4 + 2] = wv4.z; a_s[al][ak + i * 4 + 3] = wv4.w;
            }
            const size_t voff = (size_t)(b * 32 + vl) * 512 + kc * 64 + vk;
#pragma unroll
            for (int i = 0; i < 2; ++i) {
                float4 p0 = *(const float4*)(vtp + voff + i * 4);
                float4 p1 = *(const float4*)(vtp + 131072u + voff + i * 4);
                float4 pbv = *(const float4*)(pb + kc * 64 + vk + i * 4);
                float4 wv4;
                wv4.x = p0.x + p1.x + pbv.x; wv4.y = p0.y + p1.y + pbv.y;
                wv4.z = p0.z + p1.z + pbv.z; wv4.w = p0.w + p1.w + pbv.w;
                ssv += wv4.x * wv4.x + wv4.y * wv4.y + wv4.z * wv4.z + wv4.w * wv4.w;
                v_s[vl][vk + i * 4 + 0] = wv4.x; v_s[vl][vk + i * 4 + 1] = wv4.y;
                v_s[vl][vk + i * 4 + 2] = wv4.z; v_s[vl][vk + i * 4 + 3] = wv4.w;
            }
        }
        __syncthreads();
#pragma unroll 2
        for (int k = 0; k < 64; ++k) {
            float v0 = v_s[rg * 2 + 0][k];
            float v1 = v_s[rg * 2 + 1][k];
            float x0 = a_s[lg * 4 + 0][k];
            float x1 = a_s[lg * 4 + 1][k];
            float x2 = a_s[lg * 4 + 2][k];
            float x3 = a_s[lg * 4 + 3][k];
            c00 += v0 * x0; c01 += v0 * x1; c02 += v0 * x2; c03 += v0 * x3;
            c10 += v1 * x0; c11 += v1 * x1; c12 += v1 * x2; c13 += v1 * x3;
        }
    }
    ssa += __shfl_xor(ssa, 1); ssa += __shfl_xor(ssa, 2);
    if ((tid & 3) == 0) rinv_a[al] = rsqrtf(ssa);
    ssv += __shfl_xor(ssv, 1); ssv += __shfl_xor(ssv, 2); ssv += __shfl_xor(ssv, 4);
    if ((tid & 7) == 0) rinv_v[vl] = rsqrtf(ssv);
    __syncthreads();
    const float sc = __expf(ls[0]);
    const float bias = lb[0];
    float ra0 = rinv_a[lg * 4 + 0], ra1 = rinv_a[lg * 4 + 1];
    float ra2 = rinv_a[lg * 4 + 2], ra3 = rinv_a[lg * 4 + 3];
    float accs[2][4] = {{c00,c01,c02,c03},{c10,c11,c12,c13}};
#pragma unroll
    for (int cr = 0; cr < 2; ++cr) {
        int t = rg * 2 + cr;
        float rv = rinv_v[t] * sc;
        float4 o;
        o.x = accs[cr][0] * rv * ra0 + bias;
        o.y = accs[cr][1] * rv * ra1 + bias;
        o.z = accs[cr][2] * rv * ra2 + bias;
        o.w = accs[cr][3] * rv * ra3 + bias;
        *(float4*)(out + (size_t)b * 65536 + (size_t)t * 2048 + lc * 64 + lg * 4) = o;
    }
}

// ---------------- launch ----------------
extern "C" void kernel_launch(void* const* d_in, const int* in_sizes, int n_in,
                              void* d_out, int out_size, void* d_ws, size_t ws_size,
                              hipStream_t stream) {
    (void)in_sizes; (void)n_in; (void)out_size;
    const float* video = (const float*)d_in[0];
    const float* audio = (const float*)d_in[1];
    const float* probe = (const float*)d_in[2];
    const float* wq    = (const float*)d_in[3];
    const float* wk    = (const float*)d_in[4];
    const float* wv    = (const float*)d_in[5];
    const float* bq    = (const float*)d_in[6];
    const float* bk    = (const float*)d_in[7];
    const float* bv    = (const float*)d_in[8];
    const float* wo    = (const float*)d_in[9];
    const float* bo    = (const float*)d_in[10];
    const float* lng   = (const float*)d_in[11];
    const float* lnb   = (const float*)d_in[12];
    const float* pw    = (const float*)d_in[13];
    const float* pb    = (const float*)d_in[14];
    const float* ls    = (const float*)d_in[15];
    const float* lb    = (const float*)d_in[16];
    float* ws  = (float*)d_ws;
    float* out = (float*)d_out;
    if (ws_size < WS_FLOATS * sizeof(float)) return;

    float* qwt  = ws + OFF_QWT;
    float* qbs  = ws + OFF_QB;
    float* qf   = ws + OFF_QF;
    float* ctxx = ws + OFF_CTXX;
    float* ctxp = ws + OFF_CTXP;
    float* poolp= ws + OFF_POOLP;
    float* lno  = ws + OFF_LNO;
    float* vtp  = ws + OFF_VTP;

    k_qflat<<<dim3(1024), dim3(256), 0, stream>>>(probe, wq, bq, qf);
    k_qwt<<<dim3(16, 16), dim3(64), 0, stream>>>(qf, wk, bk, qwt, qbs);
    k1_attn<<<dim3(256), dim3(1024), 0, stream>>>(video, qwt, qbs, ctxx);
    // G1: ctxx (head-block diagonal) @ wv^T -> ctxp   [K=1024 split 2]
    k_gemm2<0><<<dim3(16, 16, 2), dim3(256), 0, stream>>>(ctxx, nullptr, nullptr, wv, ctxp,
                                                          16384u, 1024u, 1024u);
    // G2: (ctxp0+ctxp1+bv) @ wo^T -> poolp            [K=1024 split 2]
    k_gemm2<1><<<dim3(16, 16, 2), dim3(256), 0, stream>>>(ctxp, ctxp + 262144u, bv, wo, poolp,
                                                          1024u, 0u, 1024u);
    k_ln<<<dim3(256), dim3(256), 0, stream>>>(poolp, bo, lng, lnb, lno);
    // G3: lno @ pw^T -> vtp                           [K=1024 split 2]
    k_gemm2<0><<<dim3(16, 8, 2), dim3(256), 0, stream>>>(lno, nullptr, nullptr, pw, vtp,
                                                         1024u, 0u, 512u);
    k_sim<<<dim3(32, 8), dim3(256), 0, stream>>>(vtp, pb, audio, ls, lb, out);
}

// Round 5
// 649.823 us; speedup vs baseline: 1.6185x; 1.6185x over previous
//
#include <hip/hip_runtime.h>

// ---------------- problem constants ----------------
// B=8, T=32, S=256, DV=1024, NH=16, dh=64, DA=512, L2=2048
// video_x: [8, 8192, 1024] f32   audio_x: [8, 2048, 512] f32
// out: [8, 32, 2048] f32
//
// Pipeline (all f32):
//  qf = probe@wqT+bq ; qwt[d][h] = (1/8)*sum_{e in h} qf[e]*wk[e][d] ; qbs[h]
//  k1: per (b,t): score[s][h]=x[s,:].qwt[:,h]+qbs[h]; p=exp(score); ctxx[h][d]=sum_s p*x (/l)
//      SPLIT mode: two blocks per (b,t), S-halves, raw partials + l-partials
//  linv[bt][h] = 1/(l0+l1)
//  G1: ctx_part = ((P0+P1)*linv)(head-block) @ wv^T  (K-split 2 -> ctxp)
//  G2: pool_part = (ctxp0+ctxp1+bv) @ wo^T           (K-split 2 -> poolp)
//  LN: lno = LN(poolp0+poolp1+bo)
//  G3: vt_part = lno @ pw^T                          (K-split 2 -> vtp)
//  sim: (norm(vtp0+vtp1+pb) . norm(audio)) * exp(ls) + lb

// ---- split-path ws layout (float offsets), ~40 MB ----
#define SP_QWT    0u                       // [1024][16]
#define SP_QB     16384u                   // [16]
#define SP_QF     16400u                   // [1024]
#define SP_LP     17424u                   // [2][256][16] = 8192
#define SP_LINV   25616u                   // [256][16] = 4096
#define SP_P0     32768u                   // [256][16][1024] = 4194304
#define SP_P1     4227072u                 // [256][16][1024] = 4194304
#define SP_CTXP   8421376u                 // [2][256][1024] = 524288
#define SP_POOLP  8945664u                 // [2][256][1024] = 524288
#define SP_LNO    9469952u                 // [256][1024]    = 262144
#define SP_VTP    9732096u                 // [2][256][512]  = 262144
#define SP_FLOATS 9994240u                 // 39.98 MB

// ---- fallback (R3) ws layout, 23.1 MB ----
#define FB_QWT    0u
#define FB_QB     16384u
#define FB_QF     16400u
#define FB_CTXX   18432u                   // [256][16][1024]
#define FB_CTXP   4212736u
#define FB_POOLP  4737024u
#define FB_LNO    5261312u
#define FB_VTP    5523456u
#define FB_FLOATS 5785600u

// ---------------- K0a: q_flat[e] = probe . wq[e,:] + bq[e] ----------------
__global__ __launch_bounds__(256) void k_qflat(const float* __restrict__ probe,
                                               const float* __restrict__ wq,
                                               const float* __restrict__ bq,
                                               float* __restrict__ qf) {
    int e = blockIdx.x, tid = threadIdx.x;
    const float* wr = wq + (size_t)e * 1024;
    float s = 0.f;
    for (int k = tid; k < 1024; k += 256) s += probe[k] * wr[k];
    s += __shfl_xor(s, 1);  s += __shfl_xor(s, 2);  s += __shfl_xor(s, 4);
    s += __shfl_xor(s, 8);  s += __shfl_xor(s, 16); s += __shfl_xor(s, 32);
    __shared__ float sm[4];
    if ((tid & 63) == 0) sm[tid >> 6] = s;
    __syncthreads();
    if (tid == 0) qf[e] = sm[0] + sm[1] + sm[2] + sm[3] + bq[e];
}

// ---------------- K0b: qwt[d][h] = (1/8) * sum_{e in h} qf[e]*wk[e][d] ----------------
__global__ __launch_bounds__(64) void k_qwt(const float* __restrict__ qf,
                                            const float* __restrict__ wk,
                                            const float* __restrict__ bk,
                                            float* __restrict__ qwt,
                                            float* __restrict__ qbs) {
    int kc = blockIdx.x, h = blockIdx.y, tid = threadIdx.x; // 64 threads = 1 wave
    int d = kc * 64 + tid;
    float s = 0.f;
    for (int e0 = 0; e0 < 64; ++e0) {
        int e = h * 64 + e0;
        s += qf[e] * wk[(size_t)e * 1024 + d];
    }
    qwt[d * 16 + h] = s * 0.125f;
    if (kc == 0) {
        float p = qf[h * 64 + tid] * bk[h * 64 + tid];
        p += __shfl_xor(p, 1);  p += __shfl_xor(p, 2);  p += __shfl_xor(p, 4);
        p += __shfl_xor(p, 8);  p += __shfl_xor(p, 16); p += __shfl_xor(p, 32);
        if (tid == 0) qbs[h] = p * 0.125f;
    }
}

// ---------------- K1: fused scores + softmax-weights + weighted x-sum ----------------
// R3-proven structure: 512 threads (8 waves), 8-row chunks, double-buffered LDS,
// register-staged prefetch, wave w -> heads {2w,2w+1}, reduce width 32.
// SPLIT=0: one block per (b,t), 32 chunks, normalized ctxx out (grid 256).
// SPLIT=1: two blocks per (b,t) (S-halves), 16 chunks, RAW partial out + l-partial
//          (grid 512; normalization folded into G1 via linv).
template<int SPLIT>
__global__ __launch_bounds__(512, 4) void k1_attn(const float* __restrict__ x,
                                                  const float* __restrict__ qwt,
                                                  const float* __restrict__ qbs,
                                                  float* __restrict__ outP,
                                                  float* __restrict__ lp_out) {
    __shared__ __align__(16) float xs[2][8][1024];   // 2 x 32 KB
    __shared__ __align__(16) float p_lds[8][16];
    __shared__ float l_lds[16];
    __shared__ float linv_lds[16];

    const int tid  = threadIdx.x;
    const int lane = tid & 63;
    const int w    = tid >> 6;          // wave 0..7
    const int hsub = lane >> 5;         // 0,1
    const int km   = lane & 31;         // reduce slice
    const int h    = w * 2 + hsub;      // head for phase A
    const int hq   = tid >> 8;          // 0,1 : heads hq*8..hq*8+7 in phase C
    const int c4   = tid & 255;         // float4 column in phase C
    const int bt   = SPLIT ? (int)(blockIdx.x >> 1) : (int)blockIdx.x;
    const int sh   = SPLIT ? (int)(blockIdx.x & 1) : 0;
    const int NCH  = SPLIT ? 16 : 32;
    const float* xb = x + (size_t)bt * 262144 + (size_t)sh * 131072;

    // qw[j*4+i] = qwt[(km*4 + 128*j + i)*16 + h]  (32 VGPRs)
    float qw[32];
#pragma unroll
    for (int j = 0; j < 8; ++j)
#pragma unroll
        for (int i = 0; i < 4; ++i)
            qw[j * 4 + i] = qwt[(km * 4 + 128 * j + i) * 16 + h];
    const float qb = qbs[h];

    float4 acc[8];
#pragma unroll
    for (int hh = 0; hh < 8; ++hh) acc[hh] = make_float4(0.f, 0.f, 0.f, 0.f);
    float l_reg = 0.f;

    // prologue: chunk 0 into registers (coalesced float4)
    float4 st[4];
#pragma unroll
    for (int i = 0; i < 4; ++i)
        st[i] = *(const float4*)(xb + (size_t)(tid + i * 512) * 4);

    for (int c = 0; c < NCH; ++c) {
        const int cur = c & 1;
        float* xw = &xs[cur][0][0];
#pragma unroll
        for (int i = 0; i < 4; ++i)
            *(float4*)(xw + (size_t)(tid + i * 512) * 4) = st[i];
        __syncthreads();                  // xs[cur] staged for all waves
        if (c < NCH - 1) {                // prefetch next chunk; in flight during A+C
            const float* nb = xb + (size_t)(c + 1) * 8192;
#pragma unroll
            for (int i = 0; i < 4; ++i)
                st[i] = *(const float4*)(nb + (size_t)(tid + i * 512) * 4);
        }
        // ---- phase A: scores + exp (all 8 rows, this wave's 2 heads) ----
#pragma unroll
        for (int r = 0; r < 8; ++r) {
            const float* xr = &xs[cur][r][0];
            float s0 = 0.f, s1 = 0.f;
#pragma unroll
            for (int j = 0; j < 8; j += 2) {
                float4 a0 = *(const float4*)&xr[km * 4 + 128 * j];
                float4 a1 = *(const float4*)&xr[km * 4 + 128 * (j + 1)];
                s0 += a0.x * qw[4 * j + 0] + a0.y * qw[4 * j + 1] + a0.z * qw[4 * j + 2] + a0.w * qw[4 * j + 3];
                s1 += a1.x * qw[4 * j + 4] + a1.y * qw[4 * j + 5] + a1.z * qw[4 * j + 6] + a1.w * qw[4 * j + 7];
            }
            float s = s0 + s1;
            s += __shfl_xor(s, 16); s += __shfl_xor(s, 8);
            s += __shfl_xor(s, 4);  s += __shfl_xor(s, 2); s += __shfl_xor(s, 1);
            if (km == 0) {
                // scores ~|0.05| -> exp with shift 0 is numerically safe here
                float pv = __expf(s + qb);
                p_lds[r][h] = pv;
                l_reg += pv;
            }
        }
        __syncthreads();                  // p_lds ready
        // ---- phase C: thread = 1 float4 column x 8 heads ----
#pragma unroll
        for (int r = 0; r < 8; ++r) {
            float4 xv = *(const float4*)&xs[cur][r][c4 * 4];
            float4 pa  = *(const float4*)&p_lds[r][hq * 8];
            float4 pb4 = *(const float4*)&p_lds[r][hq * 8 + 4];
            acc[0].x += pa.x * xv.x; acc[0].y += pa.x * xv.y; acc[0].z += pa.x * xv.z; acc[0].w += pa.x * xv.w;
            acc[1].x += pa.y * xv.x; acc[1].y += pa.y * xv.y; acc[1].z += pa.y * xv.z; acc[1].w += pa.y * xv.w;
            acc[2].x += pa.z * xv.x; acc[2].y += pa.z * xv.y; acc[2].z += pa.z * xv.z; acc[2].w += pa.z * xv.w;
            acc[3].x += pa.w * xv.x; acc[3].y += pa.w * xv.y; acc[3].z += pa.w * xv.z; acc[3].w += pa.w * xv.w;
            acc[4].x += pb4.x * xv.x; acc[4].y += pb4.x * xv.y; acc[4].z += pb4.x * xv.z; acc[4].w += pb4.x * xv.w;
            acc[5].x += pb4.y * xv.x; acc[5].y += pb4.y * xv.y; acc[5].z += pb4.y * xv.z; acc[5].w += pb4.y * xv.w;
            acc[6].x += pb4.z * xv.x; acc[6].y += pb4.z * xv.y; acc[6].z += pb4.z * xv.z; acc[6].w += pb4.z * xv.w;
            acc[7].x += pb4.w * xv.x; acc[7].y += pb4.w * xv.y; acc[7].z += pb4.w * xv.z; acc[7].w += pb4.w * xv.w;
        }
    }

    if (km == 0) l_lds[h] = l_reg;
    __syncthreads();
    if (SPLIT) {
        if (tid < 16) lp_out[sh * 4096 + bt * 16 + tid] = l_lds[tid];
        float* ob = outP + (size_t)sh * 4194304 + (size_t)bt * 16384;
#pragma unroll
        for (int hh = 0; hh < 8; ++hh)
            *(float4*)(ob + (hq * 8 + hh) * 1024 + c4 * 4) = acc[hh];
    } else {
        if (tid < 16) linv_lds[tid] = 1.0f / l_lds[tid];
        __syncthreads();
        float* ob = outP + (size_t)bt * 16384;
#pragma unroll
        for (int hh = 0; hh < 8; ++hh) {
            float li = linv_lds[hq * 8 + hh];
            float4 o = acc[hh];
            o.x *= li; o.y *= li; o.z *= li; o.w *= li;
            *(float4*)(ob + (hq * 8 + hh) * 1024 + c4 * 4) = o;
        }
    }
}

// ---------------- linv[i] = 1/(lp0[i] + lp1[i]), i < 4096 ----------------
__global__ __launch_bounds__(256) void k_linv(const float* __restrict__ lp,
                                              float* __restrict__ linv) {
    int i = blockIdx.x * 256 + threadIdx.x;
    linv[i] = 1.0f / (lp[i] + lp[4096 + i]);
}

// ---------------- K-split GEMM: outp[ks][r][e] = A_row(r)[koff:+512] . B[e, koff:+512] ----
// tile 16 rows x 64 cols, 256 threads, K-slice 512 (8 kc-steps of 64).
// FOLD=0: A_eff = A0
// FOLD=1: A_eff = A0 + A1 + biask         (K-dim bias folded)
// FOLD=2: A_eff = (A0 + A1) * linv[r][cb] (ctxx partial-combine + softmax-normalize;
//                                          only valid when cb == head, a_cstride=1024)
template<int FOLD>
__global__ __launch_bounds__(256, 2) void k_gemm2(const float* __restrict__ A0,
                                                  const float* __restrict__ A1,
                                                  const float* __restrict__ biask,
                                                  const float* __restrict__ linv,
                                                  const float* __restrict__ Bw,
                                                  float* __restrict__ outp,
                                                  unsigned a_rstride, unsigned a_cstride,
                                                  unsigned ostride) {
    __shared__ __align__(16) float a_s[16][68];
    __shared__ __align__(16) float b_s[64][68];   // col-f4 swizzled: cs=(k4+e/4)&15
    const int tid = threadIdx.x;
    const int rc = blockIdx.x;     // row-chunk (16 rows)
    const int cb = blockIdx.y;     // col-block (64 cols)
    const int ks = blockIdx.z;     // K-split 0,1
    const int koff = ks * 512;
    const int rr = tid >> 4;       // output row 0..15
    const int ee = tid & 15;       // output cols ee*4..+3

    const size_t abase = (size_t)(rc * 16 + rr) * a_rstride + (size_t)cb * a_cstride + koff;
    const float lsc = (FOLD == 2) ? linv[(rc * 16 + rr) * 16 + cb] : 0.f;

    float ac0 = 0.f, ac1 = 0.f, ac2 = 0.f, ac3 = 0.f;

    for (int kc = 0; kc < 8; ++kc) {
        __syncthreads();
        {   // stage A: 1 float4/thread
            float4 av = *(const float4*)(A0 + abase + kc * 64 + ee * 4);
            if (FOLD == 1) {
                float4 a1 = *(const float4*)(A1 + abase + kc * 64 + ee * 4);
                float4 bk4 = *(const float4*)(biask + koff + kc * 64 + ee * 4);
                av.x += a1.x + bk4.x; av.y += a1.y + bk4.y;
                av.z += a1.z + bk4.z; av.w += a1.w + bk4.w;
            } else if (FOLD == 2) {
                float4 a1 = *(const float4*)(A1 + abase + kc * 64 + ee * 4);
                av.x = (av.x + a1.x) * lsc; av.y = (av.y + a1.y) * lsc;
                av.z = (av.z + a1.z) * lsc; av.w = (av.w + a1.w) * lsc;
            }
            *(float4*)&a_s[rr][ee * 4] = av;
        }
        // stage B: 4 float4/thread, linear global -> swizzled LDS
#pragma unroll
        for (int i = 0; i < 4; ++i) {
            int f4i = tid + i * 256;
            int e = f4i >> 4, k4 = f4i & 15;
            float4 bv4 = *(const float4*)(Bw + (size_t)(cb * 64 + e) * 1024 + koff + kc * 64 + k4 * 4);
            int cs = (k4 + (e >> 2)) & 15;
            *(float4*)&b_s[e][cs * 4] = bv4;
        }
        __syncthreads();
#pragma unroll
        for (int k4 = 0; k4 < 16; ++k4) {
            float4 av = *(const float4*)&a_s[rr][k4 * 4];
            int cs = (k4 + ee) & 15;
            float4 b0 = *(const float4*)&b_s[ee * 4 + 0][cs * 4];
            float4 b1 = *(const float4*)&b_s[ee * 4 + 1][cs * 4];
            float4 b2 = *(const float4*)&b_s[ee * 4 + 2][cs * 4];
            float4 b3 = *(const float4*)&b_s[ee * 4 + 3][cs * 4];
            ac0 += av.x * b0.x + av.y * b0.y + av.z * b0.z + av.w * b0.w;
            ac1 += av.x * b1.x + av.y * b1.y + av.z * b1.z + av.w * b1.w;
            ac2 += av.x * b2.x + av.y * b2.y + av.z * b2.z + av.w * b2.w;
            ac3 += av.x * b3.x + av.y * b3.y + av.z * b3.z + av.w * b3.w;
        }
    }
    float4 o = make_float4(ac0, ac1, ac2, ac3);
    *(float4*)(outp + (size_t)ks * 256 * ostride + (size_t)(rc * 16 + rr) * ostride + cb * 64 + ee * 4) = o;
}

// ---------------- LayerNorm over D=1024, folds poolp0+poolp1+bo ----------------
__global__ __launch_bounds__(256) void k_ln(const float* __restrict__ poolp,
                                            const float* __restrict__ bo,
                                            const float* __restrict__ g,
                                            const float* __restrict__ bb,
                                            float* __restrict__ out) {
    __shared__ float sm[8];
    int row = blockIdx.x, tid = threadIdx.x;
    float4 v0 = *(const float4*)(poolp + (size_t)row * 1024 + tid * 4);
    float4 v1 = *(const float4*)(poolp + 262144u + (size_t)row * 1024 + tid * 4);
    float4 bv = *(const float4*)(bo + tid * 4);
    float4 v;
    v.x = v0.x + v1.x + bv.x; v.y = v0.y + v1.y + bv.y;
    v.z = v0.z + v1.z + bv.z; v.w = v0.w + v1.w + bv.w;
    float s = v.x + v.y + v.z + v.w;
    float q = v.x * v.x + v.y * v.y + v.z * v.z + v.w * v.w;
    s += __shfl_xor(s, 1);  q += __shfl_xor(q, 1);
    s += __shfl_xor(s, 2);  q += __shfl_xor(q, 2);
    s += __shfl_xor(s, 4);  q += __shfl_xor(q, 4);
    s += __shfl_xor(s, 8);  q += __shfl_xor(q, 8);
    s += __shfl_xor(s, 16); q += __shfl_xor(q, 16);
    s += __shfl_xor(s, 32); q += __shfl_xor(q, 32);
    if ((tid & 63) == 0) { sm[tid >> 6] = s; sm[4 + (tid >> 6)] = q; }
    __syncthreads();
    float S = sm[0] + sm[1] + sm[2] + sm[3];
    float Q = sm[4] + sm[5] + sm[6] + sm[7];
    float mu = S * (1.f / 1024.f);
    float var = Q * (1.f / 1024.f) - mu * mu;
    float rs = rsqrtf(var + 1e-6f);
    float4 gg = *(const float4*)(g + tid * 4);
    float4 be = *(const float4*)(bb + tid * 4);
    float4 o;
    o.x = (v.x - mu) * rs * gg.x + be.x;
    o.y = (v.y - mu) * rs * gg.y + be.y;
    o.z = (v.z - mu) * rs * gg.z + be.z;
    o.w = (v.w - mu) * rs * gg.w + be.w;
    *(float4*)(out + (size_t)row * 1024 + tid * 4) = o;
}

// ---------------- sim = (vt_hat . a_hat) * exp(ls) + lb ----------------
// folds vtp0+vtp1+pb; block: 32 vt rows x 64 audio rows; grid (32,8)
__global__ __launch_bounds__(256, 2) void k_sim(const float* __restrict__ vtp,
                                                const float* __restrict__ pb,
                                                const float* __restrict__ audio,
                                                const float* __restrict__ ls,
                                                const float* __restrict__ lb,
                                                float* __restrict__ out) {
    __shared__ float a_s[64][65];
    __shared__ float v_s[32][65];
    __shared__ float rinv_a[64];
    __shared__ float rinv_v[32];
    const int tid = threadIdx.x;
    const int lc = blockIdx.x;   // 0..31
    const int b  = blockIdx.y;   // 0..7
    const int al = tid >> 2, ak = (tid & 3) * 16;
    const int vl = tid >> 3, vk = (tid & 7) * 8;
    const int rg = tid >> 4, lg = tid & 15;
    float ssa = 0.f, ssv = 0.f;
    float c00=0,c01=0,c02=0,c03=0,c10=0,c11=0,c12=0,c13=0;

    for (int kc = 0; kc < 8; ++kc) {
        __syncthreads();
        {
            const float* ap = audio + (size_t)b * 1048576 + (size_t)(lc * 64 + al) * 512 + kc * 64 + ak;
#pragma unroll
            for (int i = 0; i < 4; ++i) {
                float4 wv4 = *(const float4*)(ap + i * 4);
                ssa += wv4.x * wv4.x + wv4.y * wv4.y + wv4.z * wv4.z + wv4.w * wv4.w;
                a_s[al][ak + i * 4 + 0] = wv4.x; a_s[al][ak + i * 4 + 1] = wv4.y;
                a_s[al][ak + i * 4 + 2] = wv4.z; a_s[al][ak + i * 4 + 3] = wv4.w;
            }
            const size_t voff = (size_t)(b * 32 + vl) * 512 + kc * 64 + vk;
#pragma unroll
            for (int i = 0; i < 2; ++i) {
                float4 p0 = *(const float4*)(vtp + voff + i * 4);
                float4 p1 = *(const float4*)(vtp + 131072u + voff + i * 4);
                float4 pbv = *(const float4*)(pb + kc * 64 + vk + i * 4);
                float4 wv4;
                wv4.x = p0.x + p1.x + pbv.x; wv4.y = p0.y + p1.y + pbv.y;
                wv4.z = p0.z + p1.z + pbv.z; wv4.w = p0.w + p1.w + pbv.w;
                ssv += wv4.x * wv4.x + wv4.y * wv4.y + wv4.z * wv4.z + wv4.w * wv4.w;
                v_s[vl][vk + i * 4 + 0] = wv4.x; v_s[vl][vk + i * 4 + 1] = wv4.y;
                v_s[vl][vk + i * 4 + 2] = wv4.z; v_s[vl][vk + i * 4 + 3] = wv4.w;
            }
        }
        __syncthreads();
#pragma unroll 2
        for (int k = 0; k < 64; ++k) {
            float v0 = v_s[rg * 2 + 0][k];
            float v1 = v_s[rg * 2 + 1][k];
            float x0 = a_s[lg * 4 + 0][k];
            float x1 = a_s[lg * 4 + 1][k];
            float x2 = a_s[lg * 4 + 2][k];
            float x3 = a_s[lg * 4 + 3][k];
            c00 += v0 * x0; c01 += v0 * x1; c02 += v0 * x2; c03 += v0 * x3;
            c10 += v1 * x0; c11 += v1 * x1; c12 += v1 * x2; c13 += v1 * x3;
        }
    }
    ssa += __shfl_xor(ssa, 1); ssa += __shfl_xor(ssa, 2);
    if ((tid & 3) == 0) rinv_a[al] = rsqrtf(ssa);
    ssv += __shfl_xor(ssv, 1); ssv += __shfl_xor(ssv, 2); ssv += __shfl_xor(ssv, 4);
    if ((tid & 7) == 0) rinv_v[vl] = rsqrtf(ssv);
    __syncthreads();
    const float sc = __expf(ls[0]);
    const float bias = lb[0];
    float ra0 = rinv_a[lg * 4 + 0], ra1 = rinv_a[lg * 4 + 1];
    float ra2 = rinv_a[lg * 4 + 2], ra3 = rinv_a[lg * 4 + 3];
    float accs[2][4] = {{c00,c01,c02,c03},{c10,c11,c12,c13}};
#pragma unroll
    for (int cr = 0; cr < 2; ++cr) {
        int t = rg * 2 + cr;
        float rv = rinv_v[t] * sc;
        float4 o;
        o.x = accs[cr][0] * rv * ra0 + bias;
        o.y = accs[cr][1] * rv * ra1 + bias;
        o.z = accs[cr][2] * rv * ra2 + bias;
        o.w = accs[cr][3] * rv * ra3 + bias;
        *(float4*)(out + (size_t)b * 65536 + (size_t)t * 2048 + lc * 64 + lg * 4) = o;
    }
}

// ---------------- launch ----------------
extern "C" void kernel_launch(void* const* d_in, const int* in_sizes, int n_in,
                              void* d_out, int out_size, void* d_ws, size_t ws_size,
                              hipStream_t stream) {
    (void)in_sizes; (void)n_in; (void)out_size;
    const float* video = (const float*)d_in[0];
    const float* audio = (const float*)d_in[1];
    const float* probe = (const float*)d_in[2];
    const float* wq    = (const float*)d_in[3];
    const float* wk    = (const float*)d_in[4];
    const float* wv    = (const float*)d_in[5];
    const float* bq    = (const float*)d_in[6];
    const float* bk    = (const float*)d_in[7];
    const float* bv    = (const float*)d_in[8];
    const float* wo    = (const float*)d_in[9];
    const float* bo    = (const float*)d_in[10];
    const float* lng   = (const float*)d_in[11];
    const float* lnb   = (const float*)d_in[12];
    const float* pw    = (const float*)d_in[13];
    const float* pb    = (const float*)d_in[14];
    const float* ls    = (const float*)d_in[15];
    const float* lb    = (const float*)d_in[16];
    float* ws  = (float*)d_ws;
    float* out = (float*)d_out;

    if (ws_size >= SP_FLOATS * sizeof(float)) {
        // -------- split path: 2 blocks per (b,t) for k1 occupancy --------
        float* qwt  = ws + SP_QWT;
        float* qbs  = ws + SP_QB;
        float* qf   = ws + SP_QF;
        float* lp   = ws + SP_LP;
        float* linv = ws + SP_LINV;
        float* P0   = ws + SP_P0;
        float* P1   = ws + SP_P1;
        float* ctxp = ws + SP_CTXP;
        float* poolp= ws + SP_POOLP;
        float* lno  = ws + SP_LNO;
        float* vtp  = ws + SP_VTP;

        k_qflat<<<dim3(1024), dim3(256), 0, stream>>>(probe, wq, bq, qf);
        k_qwt<<<dim3(16, 16), dim3(64), 0, stream>>>(qf, wk, bk, qwt, qbs);
        k1_attn<1><<<dim3(512), dim3(512), 0, stream>>>(video, qwt, qbs, P0, lp);
        k_linv<<<dim3(16), dim3(256), 0, stream>>>(lp, linv);
        // G1: ((P0+P1)*linv)(head-block) @ wv^T -> ctxp  [K=1024 split 2]
        k_gemm2<2><<<dim3(16, 16, 2), dim3(256), 0, stream>>>(P0, P1, nullptr, linv, wv, ctxp,
                                                              16384u, 1024u, 1024u);
        k_gemm2<1><<<dim3(16, 16, 2), dim3(256), 0, stream>>>(ctxp, ctxp + 262144u, bv, nullptr, wo, poolp,
                                                              1024u, 0u, 1024u);
        k_ln<<<dim3(256), dim3(256), 0, stream>>>(poolp, bo, lng, lnb, lno);
        k_gemm2<0><<<dim3(16, 8, 2), dim3(256), 0, stream>>>(lno, nullptr, nullptr, nullptr, pw, vtp,
                                                             1024u, 0u, 512u);
        k_sim<<<dim3(32, 8), dim3(256), 0, stream>>>(vtp, pb, audio, ls, lb, out);
    } else {
        // -------- fallback: exact R3 path (23.1 MB ws) --------
        if (ws_size < FB_FLOATS * sizeof(float)) return;
        float* qwt  = ws + FB_QWT;
        float* qbs  = ws + FB_QB;
        float* qf   = ws + FB_QF;
        float* ctxx = ws + FB_CTXX;
        float* ctxp = ws + FB_CTXP;
        float* poolp= ws + FB_POOLP;
        float* lno  = ws + FB_LNO;
        float* vtp  = ws + FB_VTP;

        k_qflat<<<dim3(1024), dim3(256), 0, stream>>>(probe, wq, bq, qf);
        k_qwt<<<dim3(16, 16), dim3(64), 0, stream>>>(qf, wk, bk, qwt, qbs);
        k1_attn<0><<<dim3(256), dim3(512), 0, stream>>>(video, qwt, qbs, ctxx, nullptr);
        k_gemm2<0><<<dim3(16, 16, 2), dim3(256), 0, stream>>>(ctxx, nullptr, nullptr, nullptr, wv, ctxp,
                                                              16384u, 1024u, 1024u);
        k_gemm2<1><<<dim3(16, 16, 2), dim3(256), 0, stream>>>(ctxp, ctxp + 262144u, bv, nullptr, wo, poolp,
                                                              1024u, 0u, 1024u);
        k_ln<<<dim3(256), dim3(256), 0, stream>>>(poolp, bo, lng, lnb, lno);
        k_gemm2<0><<<dim3(16, 8, 2), dim3(256), 0, stream>>>(lno, nullptr, nullptr, nullptr, pw, vtp,
                                                             1024u, 0u, 512u);
        k_sim<<<dim3(32, 8), dim3(256), 0, stream>>>(vtp, pb, audio, ls, lb, out);
    }
}

// Round 6
// 324.024 us; speedup vs baseline: 3.2458x; 2.0055x over previous
//
#include <hip/hip_runtime.h>

// ---------------- problem constants ----------------
// B=8, T=32, S=256, DV=1024, NH=16, dh=64, DA=512, L2=2048
// video_x: [8, 8192, 1024] f32   audio_x: [8, 2048, 512] f32
// out: [8, 32, 2048] f32
//
// NOTE on __launch_bounds__: measured across R3/R4/R5, hipcc's 2nd arg acts as
// min BLOCKS per CU (CUDA semantics): (512,4) -> 8 waves/SIMD -> 64-VGPR cap ->
// spills (R5: WRITE_SIZE 328MB). (512,2) -> 4 waves/SIMD -> 128 cap -> 88 VGPR,
// no spill (R3). Keep (512,2) for k1.
//
// Pipeline (all f32):
//  qf = probe@wqT+bq ; qwt[d][h] = (1/8)*sum_{e in h} qf[e]*wk[e][d] ; qbs[h]
//  k1 (SPLIT): two blocks per (b,t) over S-halves -> raw partials P0/P1 + l-partials
//  linv[bt][h] = 1/(l0+l1)
//  G1: ctx_part = ((P0+P1)*linv)(head-block) @ wv^T  (K-split 2 -> ctxp)
//  G2: pool_part = (ctxp0+ctxp1+bv) @ wo^T           (K-split 2 -> poolp)
//  LN: lno = LN(poolp0+poolp1+bo)
//  G3: vt_part = lno @ pw^T                          (K-split 2 -> vtp)
//  sim: (norm(vtp0+vtp1+pb) . norm(audio)) * exp(ls) + lb

// ---- split-path ws layout (float offsets), ~40 MB ----
#define SP_QWT    0u                       // [1024][16]
#define SP_QB     16384u                   // [16]
#define SP_QF     16400u                   // [1024]
#define SP_LP     17424u                   // [2][256][16] = 8192
#define SP_LINV   25616u                   // [256][16] = 4096
#define SP_P0     32768u                   // [256][16][1024] = 4194304
#define SP_P1     4227072u                 // [256][16][1024] = 4194304
#define SP_CTXP   8421376u                 // [2][256][1024] = 524288
#define SP_POOLP  8945664u                 // [2][256][1024] = 524288
#define SP_LNO    9469952u                 // [256][1024]    = 262144
#define SP_VTP    9732096u                 // [2][256][512]  = 262144
#define SP_FLOATS 9994240u                 // 39.98 MB

// ---- fallback (R3) ws layout, 23.1 MB ----
#define FB_QWT    0u
#define FB_QB     16384u
#define FB_QF     16400u
#define FB_CTXX   18432u                   // [256][16][1024]
#define FB_CTXP   4212736u
#define FB_POOLP  4737024u
#define FB_LNO    5261312u
#define FB_VTP    5523456u
#define FB_FLOATS 5785600u

// ---------------- K0a: q_flat[e] = probe . wq[e,:] + bq[e] ----------------
__global__ __launch_bounds__(256) void k_qflat(const float* __restrict__ probe,
                                               const float* __restrict__ wq,
                                               const float* __restrict__ bq,
                                               float* __restrict__ qf) {
    int e = blockIdx.x, tid = threadIdx.x;
    const float* wr = wq + (size_t)e * 1024;
    float s = 0.f;
    for (int k = tid; k < 1024; k += 256) s += probe[k] * wr[k];
    s += __shfl_xor(s, 1);  s += __shfl_xor(s, 2);  s += __shfl_xor(s, 4);
    s += __shfl_xor(s, 8);  s += __shfl_xor(s, 16); s += __shfl_xor(s, 32);
    __shared__ float sm[4];
    if ((tid & 63) == 0) sm[tid >> 6] = s;
    __syncthreads();
    if (tid == 0) qf[e] = sm[0] + sm[1] + sm[2] + sm[3] + bq[e];
}

// ---------------- K0b: qwt[d][h] = (1/8) * sum_{e in h} qf[e]*wk[e][d] ----------------
__global__ __launch_bounds__(64) void k_qwt(const float* __restrict__ qf,
                                            const float* __restrict__ wk,
                                            const float* __restrict__ bk,
                                            float* __restrict__ qwt,
                                            float* __restrict__ qbs) {
    int kc = blockIdx.x, h = blockIdx.y, tid = threadIdx.x; // 64 threads = 1 wave
    int d = kc * 64 + tid;
    float s = 0.f;
    for (int e0 = 0; e0 < 64; ++e0) {
        int e = h * 64 + e0;
        s += qf[e] * wk[(size_t)e * 1024 + d];
    }
    qwt[d * 16 + h] = s * 0.125f;
    if (kc == 0) {
        float p = qf[h * 64 + tid] * bk[h * 64 + tid];
        p += __shfl_xor(p, 1);  p += __shfl_xor(p, 2);  p += __shfl_xor(p, 4);
        p += __shfl_xor(p, 8);  p += __shfl_xor(p, 16); p += __shfl_xor(p, 32);
        if (tid == 0) qbs[h] = p * 0.125f;
    }
}

// ---------------- K1: fused scores + softmax-weights + weighted x-sum ----------------
// R3-proven structure: 512 threads (8 waves), 8-row chunks, double-buffered LDS,
// register-staged prefetch, wave w -> heads {2w,2w+1}, reduce width 32.
// SPLIT=0: one block per (b,t), 32 chunks, normalized ctxx out (grid 256).
// SPLIT=1: two blocks per (b,t) (S-halves), 16 chunks, RAW partial out + l-partial
//          (grid 512 -> 2 blocks/CU; normalization folded into G1 via linv).
template<int SPLIT>
__global__ __launch_bounds__(512, 2) void k1_attn(const float* __restrict__ x,
                                                  const float* __restrict__ qwt,
                                                  const float* __restrict__ qbs,
                                                  float* __restrict__ outP,
                                                  float* __restrict__ lp_out) {
    __shared__ __align__(16) float xs[2][8][1024];   // 2 x 32 KB
    __shared__ __align__(16) float p_lds[8][16];
    __shared__ float l_lds[16];
    __shared__ float linv_lds[16];

    const int tid  = threadIdx.x;
    const int lane = tid & 63;
    const int w    = tid >> 6;          // wave 0..7
    const int hsub = lane >> 5;         // 0,1
    const int km   = lane & 31;         // reduce slice
    const int h    = w * 2 + hsub;      // head for phase A
    const int hq   = tid >> 8;          // 0,1 : heads hq*8..hq*8+7 in phase C
    const int c4   = tid & 255;         // float4 column in phase C
    const int bt   = SPLIT ? (int)(blockIdx.x >> 1) : (int)blockIdx.x;
    const int sh   = SPLIT ? (int)(blockIdx.x & 1) : 0;
    const int NCH  = SPLIT ? 16 : 32;
    const float* xb = x + (size_t)bt * 262144 + (size_t)sh * 131072;

    // qw[j*4+i] = qwt[(km*4 + 128*j + i)*16 + h]  (32 VGPRs)
    float qw[32];
#pragma unroll
    for (int j = 0; j < 8; ++j)
#pragma unroll
        for (int i = 0; i < 4; ++i)
            qw[j * 4 + i] = qwt[(km * 4 + 128 * j + i) * 16 + h];
    const float qb = qbs[h];

    float4 acc[8];
#pragma unroll
    for (int hh = 0; hh < 8; ++hh) acc[hh] = make_float4(0.f, 0.f, 0.f, 0.f);
    float l_reg = 0.f;

    // prologue: chunk 0 into registers (coalesced float4)
    float4 st[4];
#pragma unroll
    for (int i = 0; i < 4; ++i)
        st[i] = *(const float4*)(xb + (size_t)(tid + i * 512) * 4);

    for (int c = 0; c < NCH; ++c) {
        const int cur = c & 1;
        float* xw = &xs[cur][0][0];
#pragma unroll
        for (int i = 0; i < 4; ++i)
            *(float4*)(xw + (size_t)(tid + i * 512) * 4) = st[i];
        __syncthreads();                  // xs[cur] staged for all waves
        if (c < NCH - 1) {                // prefetch next chunk; in flight during A+C
            const float* nb = xb + (size_t)(c + 1) * 8192;
#pragma unroll
            for (int i = 0; i < 4; ++i)
                st[i] = *(const float4*)(nb + (size_t)(tid + i * 512) * 4);
        }
        // ---- phase A: scores + exp (all 8 rows, this wave's 2 heads) ----
#pragma unroll
        for (int r = 0; r < 8; ++r) {
            const float* xr = &xs[cur][r][0];
            float s0 = 0.f, s1 = 0.f;
#pragma unroll
            for (int j = 0; j < 8; j += 2) {
                float4 a0 = *(const float4*)&xr[km * 4 + 128 * j];
                float4 a1 = *(const float4*)&xr[km * 4 + 128 * (j + 1)];
                s0 += a0.x * qw[4 * j + 0] + a0.y * qw[4 * j + 1] + a0.z * qw[4 * j + 2] + a0.w * qw[4 * j + 3];
                s1 += a1.x * qw[4 * j + 4] + a1.y * qw[4 * j + 5] + a1.z * qw[4 * j + 6] + a1.w * qw[4 * j + 7];
            }
            float s = s0 + s1;
            s += __shfl_xor(s, 16); s += __shfl_xor(s, 8);
            s += __shfl_xor(s, 4);  s += __shfl_xor(s, 2); s += __shfl_xor(s, 1);
            if (km == 0) {
                // scores ~|0.05| -> exp with shift 0 is numerically safe here
                float pv = __expf(s + qb);
                p_lds[r][h] = pv;
                l_reg += pv;
            }
        }
        __syncthreads();                  // p_lds ready
        // ---- phase C: thread = 1 float4 column x 8 heads ----
#pragma unroll
        for (int r = 0; r < 8; ++r) {
            float4 xv = *(const float4*)&xs[cur][r][c4 * 4];
            float4 pa  = *(const float4*)&p_lds[r][hq * 8];
            float4 pb4 = *(const float4*)&p_lds[r][hq * 8 + 4];
            acc[0].x += pa.x * xv.x; acc[0].y += pa.x * xv.y; acc[0].z += pa.x * xv.z; acc[0].w += pa.x * xv.w;
            acc[1].x += pa.y * xv.x; acc[1].y += pa.y * xv.y; acc[1].z += pa.y * xv.z; acc[1].w += pa.y * xv.w;
            acc[2].x += pa.z * xv.x; acc[2].y += pa.z * xv.y; acc[2].z += pa.z * xv.z; acc[2].w += pa.z * xv.w;
            acc[3].x += pa.w * xv.x; acc[3].y += pa.w * xv.y; acc[3].z += pa.w * xv.z; acc[3].w += pa.w * xv.w;
            acc[4].x += pb4.x * xv.x; acc[4].y += pb4.x * xv.y; acc[4].z += pb4.x * xv.z; acc[4].w += pb4.x * xv.w;
            acc[5].x += pb4.y * xv.x; acc[5].y += pb4.y * xv.y; acc[5].z += pb4.y * xv.z; acc[5].w += pb4.y * xv.w;
            acc[6].x += pb4.z * xv.x; acc[6].y += pb4.z * xv.y; acc[6].z += pb4.z * xv.z; acc[6].w += pb4.z * xv.w;
            acc[7].x += pb4.w * xv.x; acc[7].y += pb4.w * xv.y; acc[7].z += pb4.w * xv.z; acc[7].w += pb4.w * xv.w;
        }
    }

    if (km == 0) l_lds[h] = l_reg;
    __syncthreads();
    if (SPLIT) {
        if (tid < 16) lp_out[sh * 4096 + bt * 16 + tid] = l_lds[tid];
        float* ob = outP + (size_t)sh * 4194304 + (size_t)bt * 16384;
#pragma unroll
        for (int hh = 0; hh < 8; ++hh)
            *(float4*)(ob + (hq * 8 + hh) * 1024 + c4 * 4) = acc[hh];
    } else {
        if (tid < 16) linv_lds[tid] = 1.0f / l_lds[tid];
        __syncthreads();
        float* ob = outP + (size_t)bt * 16384;
#pragma unroll
        for (int hh = 0; hh < 8; ++hh) {
            float li = linv_lds[hq * 8 + hh];
            float4 o = acc[hh];
            o.x *= li; o.y *= li; o.z *= li; o.w *= li;
            *(float4*)(ob + (hq * 8 + hh) * 1024 + c4 * 4) = o;
        }
    }
}

// ---------------- linv[i] = 1/(lp0[i] + lp1[i]), i < 4096 ----------------
__global__ __launch_bounds__(256) void k_linv(const float* __restrict__ lp,
                                              float* __restrict__ linv) {
    int i = blockIdx.x * 256 + threadIdx.x;
    linv[i] = 1.0f / (lp[i] + lp[4096 + i]);
}

// ---------------- K-split GEMM: outp[ks][r][e] = A_row(r)[koff:+512] . B[e, koff:+512] ----
// tile 16 rows x 64 cols, 256 threads, K-slice 512 (8 kc-steps of 64).
// FOLD=0: A_eff = A0
// FOLD=1: A_eff = A0 + A1 + biask         (K-dim bias folded)
// FOLD=2: A_eff = (A0 + A1) * linv[r][cb] (ctxx partial-combine + softmax-normalize;
//                                          only valid when cb == head, a_cstride=1024)
template<int FOLD>
__global__ __launch_bounds__(256, 2) void k_gemm2(const float* __restrict__ A0,
                                                  const float* __restrict__ A1,
                                                  const float* __restrict__ biask,
                                                  const float* __restrict__ linv,
                                                  const float* __restrict__ Bw,
                                                  float* __restrict__ outp,
                                                  unsigned a_rstride, unsigned a_cstride,
                                                  unsigned ostride) {
    __shared__ __align__(16) float a_s[16][68];
    __shared__ __align__(16) float b_s[64][68];   // col-f4 swizzled: cs=(k4+e/4)&15
    const int tid = threadIdx.x;
    const int rc = blockIdx.x;     // row-chunk (16 rows)
    const int cb = blockIdx.y;     // col-block (64 cols)
    const int ks = blockIdx.z;     // K-split 0,1
    const int koff = ks * 512;
    const int rr = tid >> 4;       // output row 0..15
    const int ee = tid & 15;       // output cols ee*4..+3

    const size_t abase = (size_t)(rc * 16 + rr) * a_rstride + (size_t)cb * a_cstride + koff;
    const float lsc = (FOLD == 2) ? linv[(rc * 16 + rr) * 16 + cb] : 0.f;

    float ac0 = 0.f, ac1 = 0.f, ac2 = 0.f, ac3 = 0.f;

    for (int kc = 0; kc < 8; ++kc) {
        __syncthreads();
        {   // stage A: 1 float4/thread
            float4 av = *(const float4*)(A0 + abase + kc * 64 + ee * 4);
            if (FOLD == 1) {
                float4 a1 = *(const float4*)(A1 + abase + kc * 64 + ee * 4);
                float4 bk4 = *(const float4*)(biask + koff + kc * 64 + ee * 4);
                av.x += a1.x + bk4.x; av.y += a1.y + bk4.y;
                av.z += a1.z + bk4.z; av.w += a1.w + bk4.w;
            } else if (FOLD == 2) {
                float4 a1 = *(const float4*)(A1 + abase + kc * 64 + ee * 4);
                av.x = (av.x + a1.x) * lsc; av.y = (av.y + a1.y) * lsc;
                av.z = (av.z + a1.z) * lsc; av.w = (av.w + a1.w) * lsc;
            }
            *(float4*)&a_s[rr][ee * 4] = av;
        }
        // stage B: 4 float4/thread, linear global -> swizzled LDS
#pragma unroll
        for (int i = 0; i < 4; ++i) {
            int f4i = tid + i * 256;
            int e = f4i >> 4, k4 = f4i & 15;
            float4 bv4 = *(const float4*)(Bw + (size_t)(cb * 64 + e) * 1024 + koff + kc * 64 + k4 * 4);
            int cs = (k4 + (e >> 2)) & 15;
            *(float4*)&b_s[e][cs * 4] = bv4;
        }
        __syncthreads();
#pragma unroll
        for (int k4 = 0; k4 < 16; ++k4) {
            float4 av = *(const float4*)&a_s[rr][k4 * 4];
            int cs = (k4 + ee) & 15;
            float4 b0 = *(const float4*)&b_s[ee * 4 + 0][cs * 4];
            float4 b1 = *(const float4*)&b_s[ee * 4 + 1][cs * 4];
            float4 b2 = *(const float4*)&b_s[ee * 4 + 2][cs * 4];
            float4 b3 = *(const float4*)&b_s[ee * 4 + 3][cs * 4];
            ac0 += av.x * b0.x + av.y * b0.y + av.z * b0.z + av.w * b0.w;
            ac1 += av.x * b1.x + av.y * b1.y + av.z * b1.z + av.w * b1.w;
            ac2 += av.x * b2.x + av.y * b2.y + av.z * b2.z + av.w * b2.w;
            ac3 += av.x * b3.x + av.y * b3.y + av.z * b3.z + av.w * b3.w;
        }
    }
    float4 o = make_float4(ac0, ac1, ac2, ac3);
    *(float4*)(outp + (size_t)ks * 256 * ostride + (size_t)(rc * 16 + rr) * ostride + cb * 64 + ee * 4) = o;
}

// ---------------- LayerNorm over D=1024, folds poolp0+poolp1+bo ----------------
__global__ __launch_bounds__(256) void k_ln(const float* __restrict__ poolp,
                                            const float* __restrict__ bo,
                                            const float* __restrict__ g,
                                            const float* __restrict__ bb,
                                            float* __restrict__ out) {
    __shared__ float sm[8];
    int row = blockIdx.x, tid = threadIdx.x;
    float4 v0 = *(const float4*)(poolp + (size_t)row * 1024 + tid * 4);
    float4 v1 = *(const float4*)(poolp + 262144u + (size_t)row * 1024 + tid * 4);
    float4 bv = *(const float4*)(bo + tid * 4);
    float4 v;
    v.x = v0.x + v1.x + bv.x; v.y = v0.y + v1.y + bv.y;
    v.z = v0.z + v1.z + bv.z; v.w = v0.w + v1.w + bv.w;
    float s = v.x + v.y + v.z + v.w;
    float q = v.x * v.x + v.y * v.y + v.z * v.z + v.w * v.w;
    s += __shfl_xor(s, 1);  q += __shfl_xor(q, 1);
    s += __shfl_xor(s, 2);  q += __shfl_xor(q, 2);
    s += __shfl_xor(s, 4);  q += __shfl_xor(q, 4);
    s += __shfl_xor(s, 8);  q += __shfl_xor(q, 8);
    s += __shfl_xor(s, 16); q += __shfl_xor(q, 16);
    s += __shfl_xor(s, 32); q += __shfl_xor(q, 32);
    if ((tid & 63) == 0) { sm[tid >> 6] = s; sm[4 + (tid >> 6)] = q; }
    __syncthreads();
    float S = sm[0] + sm[1] + sm[2] + sm[3];
    float Q = sm[4] + sm[5] + sm[6] + sm[7];
    float mu = S * (1.f / 1024.f);
    float var = Q * (1.f / 1024.f) - mu * mu;
    float rs = rsqrtf(var + 1e-6f);
    float4 gg = *(const float4*)(g + tid * 4);
    float4 be = *(const float4*)(bb + tid * 4);
    float4 o;
    o.x = (v.x - mu) * rs * gg.x + be.x;
    o.y = (v.y - mu) * rs * gg.y + be.y;
    o.z = (v.z - mu) * rs * gg.z + be.z;
    o.w = (v.w - mu) * rs * gg.w + be.w;
    *(float4*)(out + (size_t)row * 1024 + tid * 4) = o;
}

// ---------------- sim = (vt_hat . a_hat) * exp(ls) + lb ----------------
// folds vtp0+vtp1+pb; block: 32 vt rows x 64 audio rows; grid (32,8)
__global__ __launch_bounds__(256, 2) void k_sim(const float* __restrict__ vtp,
                                                const float* __restrict__ pb,
                                                const float* __restrict__ audio,
                                                const float* __restrict__ ls,
                                                const float* __restrict__ lb,
                                                float* __restrict__ out) {
    __shared__ float a_s[64][65];
    __shared__ float v_s[32][65];
    __shared__ float rinv_a[64];
    __shared__ float rinv_v[32];
    const int tid = threadIdx.x;
    const int lc = blockIdx.x;   // 0..31
    const int b  = blockIdx.y;   // 0..7
    const int al = tid >> 2, ak = (tid & 3) * 16;
    const int vl = tid >> 3, vk = (tid & 7) * 8;
    const int rg = tid >> 4, lg = tid & 15;
    float ssa = 0.f, ssv = 0.f;
    float c00=0,c01=0,c02=0,c03=0,c10=0,c11=0,c12=0,c13=0;

    for (int kc = 0; kc < 8; ++kc) {
        __syncthreads();
        {
            const float* ap = audio + (size_t)b * 1048576 + (size_t)(lc * 64 + al) * 512 + kc * 64 + ak;
#pragma unroll
            for (int i = 0; i < 4; ++i) {
                float4 wv4 = *(const float4*)(ap + i * 4);
                ssa += wv4.x * wv4.x + wv4.y * wv4.y + wv4.z * wv4.z + wv4.w * wv4.w;
                a_s[al][ak + i * 4 + 0] = wv4.x; a_s[al][ak + i * 4 + 1] = wv4.y;
                a_s[al][ak + i * 4 + 2] = wv4.z; a_s[al][ak + i * 4 + 3] = wv4.w;
            }
            const size_t voff = (size_t)(b * 32 + vl) * 512 + kc * 64 + vk;
#pragma unroll
            for (int i = 0; i < 2; ++i) {
                float4 p0 = *(const float4*)(vtp + voff + i * 4);
                float4 p1 = *(const float4*)(vtp + 131072u + voff + i * 4);
                float4 pbv = *(const float4*)(pb + kc * 64 + vk + i * 4);
                float4 wv4;
                wv4.x = p0.x + p1.x + pbv.x; wv4.y = p0.y + p1.y + pbv.y;
                wv4.z = p0.z + p1.z + pbv.z; wv4.w = p0.w + p1.w + pbv.w;
                ssv += wv4.x * wv4.x + wv4.y * wv4.y + wv4.z * wv4.z + wv4.w * wv4.w;
                v_s[vl][vk + i * 4 + 0] = wv4.x; v_s[vl][vk + i * 4 + 1] = wv4.y;
                v_s[vl][vk + i * 4 + 2] = wv4.z; v_s[vl][vk + i * 4 + 3] = wv4.w;
            }
        }
        __syncthreads();
#pragma unroll 2
        for (int k = 0; k < 64; ++k) {
            float v0 = v_s[rg * 2 + 0][k];
            float v1 = v_s[rg * 2 + 1][k];
            float x0 = a_s[lg * 4 + 0][k];
            float x1 = a_s[lg * 4 + 1][k];
            float x2 = a_s[lg * 4 + 2][k];
            float x3 = a_s[lg * 4 + 3][k];
            c00 += v0 * x0; c01 += v0 * x1; c02 += v0 * x2; c03 += v0 * x3;
            c10 += v1 * x0; c11 += v1 * x1; c12 += v1 * x2; c13 += v1 * x3;
        }
    }
    ssa += __shfl_xor(ssa, 1); ssa += __shfl_xor(ssa, 2);
    if ((tid & 3) == 0) rinv_a[al] = rsqrtf(ssa);
    ssv += __shfl_xor(ssv, 1); ssv += __shfl_xor(ssv, 2); ssv += __shfl_xor(ssv, 4);
    if ((tid & 7) == 0) rinv_v[vl] = rsqrtf(ssv);
    __syncthreads();
    const float sc = __expf(ls[0]);
    const float bias = lb[0];
    float ra0 = rinv_a[lg * 4 + 0], ra1 = rinv_a[lg * 4 + 1];
    float ra2 = rinv_a[lg * 4 + 2], ra3 = rinv_a[lg * 4 + 3];
    float accs[2][4] = {{c00,c01,c02,c03},{c10,c11,c12,c13}};
#pragma unroll
    for (int cr = 0; cr < 2; ++cr) {
        int t = rg * 2 + cr;
        float rv = rinv_v[t] * sc;
        float4 o;
        o.x = accs[cr][0] * rv * ra0 + bias;
        o.y = accs[cr][1] * rv * ra1 + bias;
        o.z = accs[cr][2] * rv * ra2 + bias;
        o.w = accs[cr][3] * rv * ra3 + bias;
        *(float4*)(out + (size_t)b * 65536 + (size_t)t * 2048 + lc * 64 + lg * 4) = o;
    }
}

// ---------------- launch ----------------
extern "C" void kernel_launch(void* const* d_in, const int* in_sizes, int n_in,
                              void* d_out, int out_size, void* d_ws, size_t ws_size,
                              hipStream_t stream) {
    (void)in_sizes; (void)n_in; (void)out_size;
    const float* video = (const float*)d_in[0];
    const float* audio = (const float*)d_in[1];
    const float* probe = (const float*)d_in[2];
    const float* wq    = (const float*)d_in[3];
    const float* wk    = (const float*)d_in[4];
    const float* wv    = (const float*)d_in[5];
    const float* bq    = (const float*)d_in[6];
    const float* bk    = (const float*)d_in[7];
    const float* bv    = (const float*)d_in[8];
    const float* wo    = (const float*)d_in[9];
    const float* bo    = (const float*)d_in[10];
    const float* lng   = (const float*)d_in[11];
    const float* lnb   = (const float*)d_in[12];
    const float* pw    = (const float*)d_in[13];
    const float* pb    = (const float*)d_in[14];
    const float* ls    = (const float*)d_in[15];
    const float* lb    = (const float*)d_in[16];
    float* ws  = (float*)d_ws;
    float* out = (float*)d_out;

    if (ws_size >= SP_FLOATS * sizeof(float)) {
        // -------- split path: 2 blocks per (b,t) for k1 occupancy --------
        float* qwt  = ws + SP_QWT;
        float* qbs  = ws + SP_QB;
        float* qf   = ws + SP_QF;
        float* lp   = ws + SP_LP;
        float* linv = ws + SP_LINV;
        float* P0   = ws + SP_P0;
        float* P1   = ws + SP_P1;
        float* ctxp = ws + SP_CTXP;
        float* poolp= ws + SP_POOLP;
        float* lno  = ws + SP_LNO;
        float* vtp  = ws + SP_VTP;

        k_qflat<<<dim3(1024), dim3(256), 0, stream>>>(probe, wq, bq, qf);
        k_qwt<<<dim3(16, 16), dim3(64), 0, stream>>>(qf, wk, bk, qwt, qbs);
        k1_attn<1><<<dim3(512), dim3(512), 0, stream>>>(video, qwt, qbs, P0, lp);
        k_linv<<<dim3(16), dim3(256), 0, stream>>>(lp, linv);
        // G1: ((P0+P1)*linv)(head-block) @ wv^T -> ctxp  [K=1024 split 2]
        k_gemm2<2><<<dim3(16, 16, 2), dim3(256), 0, stream>>>(P0, P1, nullptr, linv, wv, ctxp,
                                                              16384u, 1024u, 1024u);
        k_gemm2<1><<<dim3(16, 16, 2), dim3(256), 0, stream>>>(ctxp, ctxp + 262144u, bv, nullptr, wo, poolp,
                                                              1024u, 0u, 1024u);
        k_ln<<<dim3(256), dim3(256), 0, stream>>>(poolp, bo, lng, lnb, lno);
        k_gemm2<0><<<dim3(16, 8, 2), dim3(256), 0, stream>>>(lno, nullptr, nullptr, nullptr, pw, vtp,
                                                             1024u, 0u, 512u);
        k_sim<<<dim3(32, 8), dim3(256), 0, stream>>>(vtp, pb, audio, ls, lb, out);
    } else {
        // -------- fallback: exact R3 path (23.1 MB ws) --------
        if (ws_size < FB_FLOATS * sizeof(float)) return;
        float* qwt  = ws + FB_QWT;
        float* qbs  = ws + FB_QB;
        float* qf   = ws + FB_QF;
        float* ctxx = ws + FB_CTXX;
        float* ctxp = ws + FB_CTXP;
        float* poolp= ws + FB_POOLP;
        float* lno  = ws + FB_LNO;
        float* vtp  = ws + FB_VTP;

        k_qflat<<<dim3(1024), dim3(256), 0, stream>>>(probe, wq, bq, qf);
        k_qwt<<<dim3(16, 16), dim3(64), 0, stream>>>(qf, wk, bk, qwt, qbs);
        k1_attn<0><<<dim3(256), dim3(512), 0, stream>>>(video, qwt, qbs, ctxx, nullptr);
        k_gemm2<0><<<dim3(16, 16, 2), dim3(256), 0, stream>>>(ctxx, nullptr, nullptr, nullptr, wv, ctxp,
                                                              16384u, 1024u, 1024u);
        k_gemm2<1><<<dim3(16, 16, 2), dim3(256), 0, stream>>>(ctxp, ctxp + 262144u, bv, nullptr, wo, poolp,
                                                              1024u, 0u, 1024u);
        k_ln<<<dim3(256), dim3(256), 0, stream>>>(poolp, bo, lng, lnb, lno);
        k_gemm2<0><<<dim3(16, 8, 2), dim3(256), 0, stream>>>(lno, nullptr, nullptr, nullptr, pw, vtp,
                                                             1024u, 0u, 512u);
        k_sim<<<dim3(32, 8), dim3(256), 0, stream>>>(vtp, pb, audio, ls, lb, out);
    }
}

// Round 7
// 308.744 us; speedup vs baseline: 3.4064x; 1.0495x over previous
//
#include <hip/hip_runtime.h>

// ---------------- problem constants ----------------
// B=8, T=32, S=256, DV=1024, NH=16, dh=64, DA=512, L2=2048
// video_x: [8, 8192, 1024] f32   audio_x: [8, 2048, 512] f32
// out: [8, 32, 2048] f32
//
// NOTE __launch_bounds__ (measured R3-R6): 2nd arg behaves as min BLOCKS/CU
// (CUDA semantics): (512,4) -> 64-VGPR cap -> spills; (512,2) -> 128 cap ->
// 92 VGPR, no spill. Keep (512,2).
// NOTE LDS co-residency (measured R6): two 65KB blocks do NOT pair on a CU
// (occupancy stuck at 1 block). This round: 32.4KB/block so two pair.
//
// Pipeline (all f32):
//  qf = probe@wqT+bq ; qwt[d][h] = (1/8)*sum_{e in h} qf[e]*wk[e][d] ; qbs[h]
//  k1 (SPLIT): two blocks per (b,t) over S-halves -> raw partials P0/P1 + l-partials
//  linv[bt][h] = 1/(l0+l1)
//  G1: ctx_part = ((P0+P1)*linv)(head-block) @ wv^T  (K-split 2 -> ctxp)
//  G2: pool_part = (ctxp0+ctxp1+bv) @ wo^T           (K-split 2 -> poolp)
//  LN: lno = LN(poolp0+poolp1+bo)
//  G3: vt_part = lno @ pw^T                          (K-split 2 -> vtp)
//  sim: (norm(vtp0+vtp1+pb) . norm(audio)) * exp(ls) + lb

// ---- split-path ws layout (float offsets), ~40 MB ----
#define SP_QWT    0u                       // [1024][16]
#define SP_QB     16384u                   // [16]
#define SP_QF     16400u                   // [1024]
#define SP_LP     17424u                   // [2][256][16] = 8192
#define SP_LINV   25616u                   // [256][16] = 4096
#define SP_P0     32768u                   // [256][16][1024] = 4194304
#define SP_P1     4227072u                 // [256][16][1024] = 4194304
#define SP_CTXP   8421376u                 // [2][256][1024] = 524288
#define SP_POOLP  8945664u                 // [2][256][1024] = 524288
#define SP_LNO    9469952u                 // [256][1024]    = 262144
#define SP_VTP    9732096u                 // [2][256][512]  = 262144
#define SP_FLOATS 9994240u                 // 39.98 MB

// ---- fallback ws layout, 23.1 MB ----
#define FB_QWT    0u
#define FB_QB     16384u
#define FB_QF     16400u
#define FB_CTXX   18432u                   // [256][16][1024]
#define FB_CTXP   4212736u
#define FB_POOLP  4737024u
#define FB_LNO    5261312u
#define FB_VTP    5523456u
#define FB_FLOATS 5785600u

// ---------------- K0a: q_flat[e] = probe . wq[e,:] + bq[e] ----------------
__global__ __launch_bounds__(256) void k_qflat(const float* __restrict__ probe,
                                               const float* __restrict__ wq,
                                               const float* __restrict__ bq,
                                               float* __restrict__ qf) {
    int e = blockIdx.x, tid = threadIdx.x;
    const float* wr = wq + (size_t)e * 1024;
    float s = 0.f;
    for (int k = tid; k < 1024; k += 256) s += probe[k] * wr[k];
    s += __shfl_xor(s, 1);  s += __shfl_xor(s, 2);  s += __shfl_xor(s, 4);
    s += __shfl_xor(s, 8);  s += __shfl_xor(s, 16); s += __shfl_xor(s, 32);
    __shared__ float sm[4];
    if ((tid & 63) == 0) sm[tid >> 6] = s;
    __syncthreads();
    if (tid == 0) qf[e] = sm[0] + sm[1] + sm[2] + sm[3] + bq[e];
}

// ---------------- K0b: qwt[d][h] = (1/8) * sum_{e in h} qf[e]*wk[e][d] ----------------
__global__ __launch_bounds__(64) void k_qwt(const float* __restrict__ qf,
                                            const float* __restrict__ wk,
                                            const float* __restrict__ bk,
                                            float* __restrict__ qwt,
                                            float* __restrict__ qbs) {
    int kc = blockIdx.x, h = blockIdx.y, tid = threadIdx.x; // 64 threads = 1 wave
    int d = kc * 64 + tid;
    float s = 0.f;
    for (int e0 = 0; e0 < 64; ++e0) {
        int e = h * 64 + e0;
        s += qf[e] * wk[(size_t)e * 1024 + d];
    }
    qwt[d * 16 + h] = s * 0.125f;
    if (kc == 0) {
        float p = qf[h * 64 + tid] * bk[h * 64 + tid];
        p += __shfl_xor(p, 1);  p += __shfl_xor(p, 2);  p += __shfl_xor(p, 4);
        p += __shfl_xor(p, 8);  p += __shfl_xor(p, 16); p += __shfl_xor(p, 32);
        if (tid == 0) qbs[h] = p * 0.125f;
    }
}

// ---------------- K1: fused scores + softmax-weights + weighted x-sum ----------------
// 512 threads (8 waves), 4-ROW chunks (32.4 KB LDS -> 2 blocks/CU), double-buffered,
// register-staged prefetch, wave w -> heads {2w,2w+1}, reduce width 32.
// SPLIT=0: one block per (b,t), 64 chunks, normalized ctxx out (grid 256).
// SPLIT=1: two blocks per (b,t) (S-halves), 32 chunks, RAW partial out + l-partial
//          (grid 512 -> 2 blocks/CU; normalization folded into G1 via linv).
template<int SPLIT>
__global__ __launch_bounds__(512, 2) void k1_attn(const float* __restrict__ x,
                                                  const float* __restrict__ qwt,
                                                  const float* __restrict__ qbs,
                                                  float* __restrict__ outP,
                                                  float* __restrict__ lp_out) {
    __shared__ __align__(16) float xs[2][4][1024];   // 2 x 16 KB
    __shared__ __align__(16) float p_lds[4][16];
    __shared__ float l_lds[16];
    __shared__ float linv_lds[16];

    const int tid  = threadIdx.x;
    const int lane = tid & 63;
    const int w    = tid >> 6;          // wave 0..7
    const int hsub = lane >> 5;         // 0,1
    const int km   = lane & 31;         // reduce slice
    const int h    = w * 2 + hsub;      // head for phase A
    const int hq   = tid >> 8;          // 0,1 : heads hq*8..hq*8+7 in phase C
    const int c4   = tid & 255;         // float4 column in phase C
    const int bt   = SPLIT ? (int)(blockIdx.x >> 1) : (int)blockIdx.x;
    const int sh   = SPLIT ? (int)(blockIdx.x & 1) : 0;
    const int NCH  = SPLIT ? 32 : 64;   // chunks of 4 rows
    const float* xb = x + (size_t)bt * 262144 + (size_t)sh * 131072;

    // qw[j*4+i] = qwt[(km*4 + 128*j + i)*16 + h]  (32 VGPRs)
    float qw[32];
#pragma unroll
    for (int j = 0; j < 8; ++j)
#pragma unroll
        for (int i = 0; i < 4; ++i)
            qw[j * 4 + i] = qwt[(km * 4 + 128 * j + i) * 16 + h];
    const float qb = qbs[h];

    float4 acc[8];
#pragma unroll
    for (int hh = 0; hh < 8; ++hh) acc[hh] = make_float4(0.f, 0.f, 0.f, 0.f);
    float l_reg = 0.f;

    // prologue: chunk 0 (4 rows = 1024 float4) into registers
    float4 st[2];
#pragma unroll
    for (int i = 0; i < 2; ++i)
        st[i] = *(const float4*)(xb + (size_t)(tid + i * 512) * 4);

    for (int c = 0; c < NCH; ++c) {
        const int cur = c & 1;
        float* xw = &xs[cur][0][0];
#pragma unroll
        for (int i = 0; i < 2; ++i)
            *(float4*)(xw + (size_t)(tid + i * 512) * 4) = st[i];
        __syncthreads();                  // xs[cur] staged for all waves
        if (c < NCH - 1) {                // prefetch next chunk; in flight during A+C
            const float* nb = xb + (size_t)(c + 1) * 4096;
#pragma unroll
            for (int i = 0; i < 2; ++i)
                st[i] = *(const float4*)(nb + (size_t)(tid + i * 512) * 4);
        }
        // ---- phase A: scores + exp (4 rows, this wave's 2 heads) ----
#pragma unroll
        for (int r = 0; r < 4; ++r) {
            const float* xr = &xs[cur][r][0];
            float s0 = 0.f, s1 = 0.f;
#pragma unroll
            for (int j = 0; j < 8; j += 2) {
                float4 a0 = *(const float4*)&xr[km * 4 + 128 * j];
                float4 a1 = *(const float4*)&xr[km * 4 + 128 * (j + 1)];
                s0 += a0.x * qw[4 * j + 0] + a0.y * qw[4 * j + 1] + a0.z * qw[4 * j + 2] + a0.w * qw[4 * j + 3];
                s1 += a1.x * qw[4 * j + 4] + a1.y * qw[4 * j + 5] + a1.z * qw[4 * j + 6] + a1.w * qw[4 * j + 7];
            }
            float s = s0 + s1;
            s += __shfl_xor(s, 16); s += __shfl_xor(s, 8);
            s += __shfl_xor(s, 4);  s += __shfl_xor(s, 2); s += __shfl_xor(s, 1);
            if (km == 0) {
                // scores ~|0.05| -> exp with shift 0 is numerically safe here
                float pv = __expf(s + qb);
                p_lds[r][h] = pv;
                l_reg += pv;
            }
        }
        __syncthreads();                  // p_lds ready
        // ---- phase C: thread = 1 float4 column x 8 heads, 4 rows ----
#pragma unroll
        for (int r = 0; r < 4; ++r) {
            float4 xv = *(const float4*)&xs[cur][r][c4 * 4];
            float4 pa  = *(const float4*)&p_lds[r][hq * 8];
            float4 pb4 = *(const float4*)&p_lds[r][hq * 8 + 4];
            acc[0].x += pa.x * xv.x; acc[0].y += pa.x * xv.y; acc[0].z += pa.x * xv.z; acc[0].w += pa.x * xv.w;
            acc[1].x += pa.y * xv.x; acc[1].y += pa.y * xv.y; acc[1].z += pa.y * xv.z; acc[1].w += pa.y * xv.w;
            acc[2].x += pa.z * xv.x; acc[2].y += pa.z * xv.y; acc[2].z += pa.z * xv.z; acc[2].w += pa.z * xv.w;
            acc[3].x += pa.w * xv.x; acc[3].y += pa.w * xv.y; acc[3].z += pa.w * xv.z; acc[3].w += pa.w * xv.w;
            acc[4].x += pb4.x * xv.x; acc[4].y += pb4.x * xv.y; acc[4].z += pb4.x * xv.z; acc[4].w += pb4.x * xv.w;
            acc[5].x += pb4.y * xv.x; acc[5].y += pb4.y * xv.y; acc[5].z += pb4.y * xv.z; acc[5].w += pb4.y * xv.w;
            acc[6].x += pb4.z * xv.x; acc[6].y += pb4.z * xv.y; acc[6].z += pb4.z * xv.z; acc[6].w += pb4.z * xv.w;
            acc[7].x += pb4.w * xv.x; acc[7].y += pb4.w * xv.y; acc[7].z += pb4.w * xv.z; acc[7].w += pb4.w * xv.w;
        }
    }

    if (km == 0) l_lds[h] = l_reg;
    __syncthreads();
    if (SPLIT) {
        if (tid < 16) lp_out[sh * 4096 + bt * 16 + tid] = l_lds[tid];
        float* ob = outP + (size_t)sh * 4194304 + (size_t)bt * 16384;
#pragma unroll
        for (int hh = 0; hh < 8; ++hh)
            *(float4*)(ob + (hq * 8 + hh) * 1024 + c4 * 4) = acc[hh];
    } else {
        if (tid < 16) linv_lds[tid] = 1.0f / l_lds[tid];
        __syncthreads();
        float* ob = outP + (size_t)bt * 16384;
#pragma unroll
        for (int hh = 0; hh < 8; ++hh) {
            float li = linv_lds[hq * 8 + hh];
            float4 o = acc[hh];
            o.x *= li; o.y *= li; o.z *= li; o.w *= li;
            *(float4*)(ob + (hq * 8 + hh) * 1024 + c4 * 4) = o;
        }
    }
}

// ---------------- linv[i] = 1/(lp0[i] + lp1[i]), i < 4096 ----------------
__global__ __launch_bounds__(256) void k_linv(const float* __restrict__ lp,
                                              float* __restrict__ linv) {
    int i = blockIdx.x * 256 + threadIdx.x;
    linv[i] = 1.0f / (lp[i] + lp[4096 + i]);
}

// ---------------- K-split GEMM: outp[ks][r][e] = A_row(r)[koff:+512] . B[e, koff:+512] ----
// tile 16 rows x 64 cols, 256 threads, K-slice 512 (8 kc-steps of 64).
// FOLD=0: A_eff = A0
// FOLD=1: A_eff = A0 + A1 + biask         (K-dim bias folded)
// FOLD=2: A_eff = (A0 + A1) * linv[r][cb] (partial-combine + softmax-normalize)
template<int FOLD>
__global__ __launch_bounds__(256, 2) void k_gemm2(const float* __restrict__ A0,
                                                  const float* __restrict__ A1,
                                                  const float* __restrict__ biask,
                                                  const float* __restrict__ linv,
                                                  const float* __restrict__ Bw,
                                                  float* __restrict__ outp,
                                                  unsigned a_rstride, unsigned a_cstride,
                                                  unsigned ostride) {
    __shared__ __align__(16) float a_s[16][68];
    __shared__ __align__(16) float b_s[64][68];   // col-f4 swizzled: cs=(k4+e/4)&15
    const int tid = threadIdx.x;
    const int rc = blockIdx.x;     // row-chunk (16 rows)
    const int cb = blockIdx.y;     // col-block (64 cols)
    const int ks = blockIdx.z;     // K-split 0,1
    const int koff = ks * 512;
    const int rr = tid >> 4;       // output row 0..15
    const int ee = tid & 15;       // output cols ee*4..+3

    const size_t abase = (size_t)(rc * 16 + rr) * a_rstride + (size_t)cb * a_cstride + koff;
    const float lsc = (FOLD == 2) ? linv[(rc * 16 + rr) * 16 + cb] : 0.f;

    float ac0 = 0.f, ac1 = 0.f, ac2 = 0.f, ac3 = 0.f;

    for (int kc = 0; kc < 8; ++kc) {
        __syncthreads();
        {   // stage A: 1 float4/thread
            float4 av = *(const float4*)(A0 + abase + kc * 64 + ee * 4);
            if (FOLD == 1) {
                float4 a1 = *(const float4*)(A1 + abase + kc * 64 + ee * 4);
                float4 bk4 = *(const float4*)(biask + koff + kc * 64 + ee * 4);
                av.x += a1.x + bk4.x; av.y += a1.y + bk4.y;
                av.z += a1.z + bk4.z; av.w += a1.w + bk4.w;
            } else if (FOLD == 2) {
                float4 a1 = *(const float4*)(A1 + abase + kc * 64 + ee * 4);
                av.x = (av.x + a1.x) * lsc; av.y = (av.y + a1.y) * lsc;
                av.z = (av.z + a1.z) * lsc; av.w = (av.w + a1.w) * lsc;
            }
            *(float4*)&a_s[rr][ee * 4] = av;
        }
        // stage B: 4 float4/thread, linear global -> swizzled LDS
#pragma unroll
        for (int i = 0; i < 4; ++i) {
            int f4i = tid + i * 256;
            int e = f4i >> 4, k4 = f4i & 15;
            float4 bv4 = *(const float4*)(Bw + (size_t)(cb * 64 + e) * 1024 + koff + kc * 64 + k4 * 4);
            int cs = (k4 + (e >> 2)) & 15;
            *(float4*)&b_s[e][cs * 4] = bv4;
        }
        __syncthreads();
#pragma unroll
        for (int k4 = 0; k4 < 16; ++k4) {
            float4 av = *(const float4*)&a_s[rr][k4 * 4];
            int cs = (k4 + ee) & 15;
            float4 b0 = *(const float4*)&b_s[ee * 4 + 0][cs * 4];
            float4 b1 = *(const float4*)&b_s[ee * 4 + 1][cs * 4];
            float4 b2 = *(const float4*)&b_s[ee * 4 + 2][cs * 4];
            float4 b3 = *(const float4*)&b_s[ee * 4 + 3][cs * 4];
            ac0 += av.x * b0.x + av.y * b0.y + av.z * b0.z + av.w * b0.w;
            ac1 += av.x * b1.x + av.y * b1.y + av.z * b1.z + av.w * b1.w;
            ac2 += av.x * b2.x + av.y * b2.y + av.z * b2.z + av.w * b2.w;
            ac3 += av.x * b3.x + av.y * b3.y + av.z * b3.z + av.w * b3.w;
        }
    }
    float4 o = make_float4(ac0, ac1, ac2, ac3);
    *(float4*)(outp + (size_t)ks * 256 * ostride + (size_t)(rc * 16 + rr) * ostride + cb * 64 + ee * 4) = o;
}

// ---------------- LayerNorm over D=1024, folds poolp0+poolp1+bo ----------------
__global__ __launch_bounds__(256) void k_ln(const float* __restrict__ poolp,
                                            const float* __restrict__ bo,
                                            const float* __restrict__ g,
                                            const float* __restrict__ bb,
                                            float* __restrict__ out) {
    __shared__ float sm[8];
    int row = blockIdx.x, tid = threadIdx.x;
    float4 v0 = *(const float4*)(poolp + (size_t)row * 1024 + tid * 4);
    float4 v1 = *(const float4*)(poolp + 262144u + (size_t)row * 1024 + tid * 4);
    float4 bv = *(const float4*)(bo + tid * 4);
    float4 v;
    v.x = v0.x + v1.x + bv.x; v.y = v0.y + v1.y + bv.y;
    v.z = v0.z + v1.z + bv.z; v.w = v0.w + v1.w + bv.w;
    float s = v.x + v.y + v.z + v.w;
    float q = v.x * v.x + v.y * v.y + v.z * v.z + v.w * v.w;
    s += __shfl_xor(s, 1);  q += __shfl_xor(q, 1);
    s += __shfl_xor(s, 2);  q += __shfl_xor(q, 2);
    s += __shfl_xor(s, 4);  q += __shfl_xor(q, 4);
    s += __shfl_xor(s, 8);  q += __shfl_xor(q, 8);
    s += __shfl_xor(s, 16); q += __shfl_xor(q, 16);
    s += __shfl_xor(s, 32); q += __shfl_xor(q, 32);
    if ((tid & 63) == 0) { sm[tid >> 6] = s; sm[4 + (tid >> 6)] = q; }
    __syncthreads();
    float S = sm[0] + sm[1] + sm[2] + sm[3];
    float Q = sm[4] + sm[5] + sm[6] + sm[7];
    float mu = S * (1.f / 1024.f);
    float var = Q * (1.f / 1024.f) - mu * mu;
    float rs = rsqrtf(var + 1e-6f);
    float4 gg = *(const float4*)(g + tid * 4);
    float4 be = *(const float4*)(bb + tid * 4);
    float4 o;
    o.x = (v.x - mu) * rs * gg.x + be.x;
    o.y = (v.y - mu) * rs * gg.y + be.y;
    o.z = (v.z - mu) * rs * gg.z + be.z;
    o.w = (v.w - mu) * rs * gg.w + be.w;
    *(float4*)(out + (size_t)row * 1024 + tid * 4) = o;
}

// ---------------- sim = (vt_hat . a_hat) * exp(ls) + lb ----------------
// folds vtp0+vtp1+pb; block: 32 vt rows x 64 audio rows; grid (32,8)
__global__ __launch_bounds__(256, 2) void k_sim(const float* __restrict__ vtp,
                                                const float* __restrict__ pb,
                                                const float* __restrict__ audio,
                                                const float* __restrict__ ls,
                                                const float* __restrict__ lb,
                                                float* __restrict__ out) {
    __shared__ float a_s[64][65];
    __shared__ float v_s[32][65];
    __shared__ float rinv_a[64];
    __shared__ float rinv_v[32];
    const int tid = threadIdx.x;
    const int lc = blockIdx.x;   // 0..31
    const int b  = blockIdx.y;   // 0..7
    const int al = tid >> 2, ak = (tid & 3) * 16;
    const int vl = tid >> 3, vk = (tid & 7) * 8;
    const int rg = tid >> 4, lg = tid & 15;
    float ssa = 0.f, ssv = 0.f;
    float c00=0,c01=0,c02=0,c03=0,c10=0,c11=0,c12=0,c13=0;

    for (int kc = 0; kc < 8; ++kc) {
        __syncthreads();
        {
            const float* ap = audio + (size_t)b * 1048576 + (size_t)(lc * 64 + al) * 512 + kc * 64 + ak;
#pragma unroll
            for (int i = 0; i < 4; ++i) {
                float4 wv4 = *(const float4*)(ap + i * 4);
                ssa += wv4.x * wv4.x + wv4.y * wv4.y + wv4.z * wv4.z + wv4.w * wv4.w;
                a_s[al][ak + i * 4 + 0] = wv4.x; a_s[al][ak + i * 4 + 1] = wv4.y;
                a_s[al][ak + i * 4 + 2] = wv4.z; a_s[al][ak + i * 4 + 3] = wv4.w;
            }
            const size_t voff = (size_t)(b * 32 + vl) * 512 + kc * 64 + vk;
#pragma unroll
            for (int i = 0; i < 2; ++i) {
                float4 p0 = *(const float4*)(vtp + voff + i * 4);
                float4 p1 = *(const float4*)(vtp + 131072u + voff + i * 4);
                float4 pbv = *(const float4*)(pb + kc * 64 + vk + i * 4);
                float4 wv4;
                wv4.x = p0.x + p1.x + pbv.x; wv4.y = p0.y + p1.y + pbv.y;
                wv4.z = p0.z + p1.z + pbv.z; wv4.w = p0.w + p1.w + pbv.w;
                ssv += wv4.x * wv4.x + wv4.y * wv4.y + wv4.z * wv4.z + wv4.w * wv4.w;
                v_s[vl][vk + i * 4 + 0] = wv4.x; v_s[vl][vk + i * 4 + 1] = wv4.y;
                v_s[vl][vk + i * 4 + 2] = wv4.z; v_s[vl][vk + i * 4 + 3] = wv4.w;
            }
        }
        __syncthreads();
#pragma unroll 2
        for (int k = 0; k < 64; ++k) {
            float v0 = v_s[rg * 2 + 0][k];
            float v1 = v_s[rg * 2 + 1][k];
            float x0 = a_s[lg * 4 + 0][k];
            float x1 = a_s[lg * 4 + 1][k];
            float x2 = a_s[lg * 4 + 2][k];
            float x3 = a_s[lg * 4 + 3][k];
            c00 += v0 * x0; c01 += v0 * x1; c02 += v0 * x2; c03 += v0 * x3;
            c10 += v1 * x0; c11 += v1 * x1; c12 += v1 * x2; c13 += v1 * x3;
        }
    }
    ssa += __shfl_xor(ssa, 1); ssa += __shfl_xor(ssa, 2);
    if ((tid & 3) == 0) rinv_a[al] = rsqrtf(ssa);
    ssv += __shfl_xor(ssv, 1); ssv += __shfl_xor(ssv, 2); ssv += __shfl_xor(ssv, 4);
    if ((tid & 7) == 0) rinv_v[vl] = rsqrtf(ssv);
    __syncthreads();
    const float sc = __expf(ls[0]);
    const float bias = lb[0];
    float ra0 = rinv_a[lg * 4 + 0], ra1 = rinv_a[lg * 4 + 1];
    float ra2 = rinv_a[lg * 4 + 2], ra3 = rinv_a[lg * 4 + 3];
    float accs[2][4] = {{c00,c01,c02,c03},{c10,c11,c12,c13}};
#pragma unroll
    for (int cr = 0; cr < 2; ++cr) {
        int t = rg * 2 + cr;
        float rv = rinv_v[t] * sc;
        float4 o;
        o.x = accs[cr][0] * rv * ra0 + bias;
        o.y = accs[cr][1] * rv * ra1 + bias;
        o.z = accs[cr][2] * rv * ra2 + bias;
        o.w = accs[cr][3] * rv * ra3 + bias;
        *(float4*)(out + (size_t)b * 65536 + (size_t)t * 2048 + lc * 64 + lg * 4) = o;
    }
}

// ---------------- launch ----------------
extern "C" void kernel_launch(void* const* d_in, const int* in_sizes, int n_in,
                              void* d_out, int out_size, void* d_ws, size_t ws_size,
                              hipStream_t stream) {
    (void)in_sizes; (void)n_in; (void)out_size;
    const float* video = (const float*)d_in[0];
    const float* audio = (const float*)d_in[1];
    const float* probe = (const float*)d_in[2];
    const float* wq    = (const float*)d_in[3];
    const float* wk    = (const float*)d_in[4];
    const float* wv    = (const float*)d_in[5];
    const float* bq    = (const float*)d_in[6];
    const float* bk    = (const float*)d_in[7];
    const float* bv    = (const float*)d_in[8];
    const float* wo    = (const float*)d_in[9];
    const float* bo    = (const float*)d_in[10];
    const float* lng   = (const float*)d_in[11];
    const float* lnb   = (const float*)d_in[12];
    const float* pw    = (const float*)d_in[13];
    const float* pb    = (const float*)d_in[14];
    const float* ls    = (const float*)d_in[15];
    const float* lb    = (const float*)d_in[16];
    float* ws  = (float*)d_ws;
    float* out = (float*)d_out;

    if (ws_size >= SP_FLOATS * sizeof(float)) {
        // -------- split path: 2 blocks per (b,t) for k1 occupancy --------
        float* qwt  = ws + SP_QWT;
        float* qbs  = ws + SP_QB;
        float* qf   = ws + SP_QF;
        float* lp   = ws + SP_LP;
        float* linv = ws + SP_LINV;
        float* P0   = ws + SP_P0;
        float* P1   = ws + SP_P1;
        float* ctxp = ws + SP_CTXP;
        float* poolp= ws + SP_POOLP;
        float* lno  = ws + SP_LNO;
        float* vtp  = ws + SP_VTP;

        k_qflat<<<dim3(1024), dim3(256), 0, stream>>>(probe, wq, bq, qf);
        k_qwt<<<dim3(16, 16), dim3(64), 0, stream>>>(qf, wk, bk, qwt, qbs);
        k1_attn<1><<<dim3(512), dim3(512), 0, stream>>>(video, qwt, qbs, P0, lp);
        k_linv<<<dim3(16), dim3(256), 0, stream>>>(lp, linv);
        // G1: ((P0+P1)*linv)(head-block) @ wv^T -> ctxp  [K=1024 split 2]
        k_gemm2<2><<<dim3(16, 16, 2), dim3(256), 0, stream>>>(P0, P1, nullptr, linv, wv, ctxp,
                                                              16384u, 1024u, 1024u);
        k_gemm2<1><<<dim3(16, 16, 2), dim3(256), 0, stream>>>(ctxp, ctxp + 262144u, bv, nullptr, wo, poolp,
                                                              1024u, 0u, 1024u);
        k_ln<<<dim3(256), dim3(256), 0, stream>>>(poolp, bo, lng, lnb, lno);
        k_gemm2<0><<<dim3(16, 8, 2), dim3(256), 0, stream>>>(lno, nullptr, nullptr, nullptr, pw, vtp,
                                                             1024u, 0u, 512u);
        k_sim<<<dim3(32, 8), dim3(256), 0, stream>>>(vtp, pb, audio, ls, lb, out);
    } else {
        // -------- fallback path (23.1 MB ws) --------
        if (ws_size < FB_FLOATS * sizeof(float)) return;
        float* qwt  = ws + FB_QWT;
        float* qbs  = ws + FB_QB;
        float* qf   = ws + FB_QF;
        float* ctxx = ws + FB_CTXX;
        float* ctxp = ws + FB_CTXP;
        float* poolp= ws + FB_POOLP;
        float* lno  = ws + FB_LNO;
        float* vtp  = ws + FB_VTP;

        k_qflat<<<dim3(1024), dim3(256), 0, stream>>>(probe, wq, bq, qf);
        k_qwt<<<dim3(16, 16), dim3(64), 0, stream>>>(qf, wk, bk, qwt, qbs);
        k1_attn<0><<<dim3(256), dim3(512), 0, stream>>>(video, qwt, qbs, ctxx, nullptr);
        k_gemm2<0><<<dim3(16, 16, 2), dim3(256), 0, stream>>>(ctxx, nullptr, nullptr, nullptr, wv, ctxp,
                                                              16384u, 1024u, 1024u);
        k_gemm2<1><<<dim3(16, 16, 2), dim3(256), 0, stream>>>(ctxp, ctxp + 262144u, bv, nullptr, wo, poolp,
                                                              1024u, 0u, 1024u);
        k_ln<<<dim3(256), dim3(256), 0, stream>>>(poolp, bo, lng, lnb, lno);
        k_gemm2<0><<<dim3(16, 8, 2), dim3(256), 0, stream>>>(lno, nullptr, nullptr, nullptr, pw, vtp,
                                                             1024u, 0u, 512u);
        k_sim<<<dim3(32, 8), dim3(256), 0, stream>>>(vtp, pb, audio, ls, lb, out);
    }
}

// Round 8
// 304.136 us; speedup vs baseline: 3.4580x; 1.0152x over previous
//
#include <hip/hip_runtime.h>

// ---------------- problem constants ----------------
// B=8, T=32, S=256, DV=1024, NH=16, dh=64, DA=512, L2=2048
// video_x: [8, 8192, 1024] f32   audio_x: [8, 2048, 512] f32
// out: [8, 32, 2048] f32
//
// MEASURED (R3-R7): VGPR>64 halves wave capacity to 16/CU (m69 cliff) and a
// second 8-wave block then never co-schedules -> occupancy pinned at 1 block.
// This round: single 1024-thread block (16 waves = 4 waves/SIMD = 50% occ
// standalone), kernel engineered to ~60 live VGPRs (qw[16], acc[16]).
//
// Pipeline (all f32):
//  qf = probe@wqT+bq ; qwt[d][h] = (1/8)*sum_{e in h} qf[e]*wk[e][d] ; qbs[h]
//  k1: per (b,t): score[s][h]=x[s,:].qwt[:,h]+qbs[h]; p=exp(score);
//      ctxx[h][d] = sum_s p*x[s][d] / l[h]        (one 1024-thr block per bt)
//  G1: ctx_part = ctxx(head-block) @ wv^T         (K-split 2 -> ctxp)
//  G2: pool_part = (ctxp0+ctxp1+bv) @ wo^T        (K-split 2 -> poolp)
//  LN: lno = LN(poolp0+poolp1+bo)
//  G3: vt_part = lno @ pw^T                       (K-split 2 -> vtp)
//  sim: (norm(vtp0+vtp1+pb) . norm(audio)) * exp(ls) + lb

// ---- ws layout (float offsets), 23.1 MB ----
#define FB_QWT    0u
#define FB_QB     16384u
#define FB_QF     16400u
#define FB_CTXX   18432u                   // [256][16][1024]
#define FB_CTXP   4212736u
#define FB_POOLP  4737024u
#define FB_LNO    5261312u
#define FB_VTP    5523456u
#define FB_FLOATS 5785600u

// ---------------- K0a: q_flat[e] = probe . wq[e,:] + bq[e] ----------------
__global__ __launch_bounds__(256) void k_qflat(const float* __restrict__ probe,
                                               const float* __restrict__ wq,
                                               const float* __restrict__ bq,
                                               float* __restrict__ qf) {
    int e = blockIdx.x, tid = threadIdx.x;
    const float* wr = wq + (size_t)e * 1024;
    float s = 0.f;
    for (int k = tid; k < 1024; k += 256) s += probe[k] * wr[k];
    s += __shfl_xor(s, 1);  s += __shfl_xor(s, 2);  s += __shfl_xor(s, 4);
    s += __shfl_xor(s, 8);  s += __shfl_xor(s, 16); s += __shfl_xor(s, 32);
    __shared__ float sm[4];
    if ((tid & 63) == 0) sm[tid >> 6] = s;
    __syncthreads();
    if (tid == 0) qf[e] = sm[0] + sm[1] + sm[2] + sm[3] + bq[e];
}

// ---------------- K0b: qwt[d][h] = (1/8) * sum_{e in h} qf[e]*wk[e][d] ----------------
__global__ __launch_bounds__(64) void k_qwt(const float* __restrict__ qf,
                                            const float* __restrict__ wk,
                                            const float* __restrict__ bk,
                                            float* __restrict__ qwt,
                                            float* __restrict__ qbs) {
    int kc = blockIdx.x, h = blockIdx.y, tid = threadIdx.x; // 64 threads = 1 wave
    int d = kc * 64 + tid;
    float s = 0.f;
    for (int e0 = 0; e0 < 64; ++e0) {
        int e = h * 64 + e0;
        s += qf[e] * wk[(size_t)e * 1024 + d];
    }
    qwt[d * 16 + h] = s * 0.125f;
    if (kc == 0) {
        float p = qf[h * 64 + tid] * bk[h * 64 + tid];
        p += __shfl_xor(p, 1);  p += __shfl_xor(p, 2);  p += __shfl_xor(p, 4);
        p += __shfl_xor(p, 8);  p += __shfl_xor(p, 16); p += __shfl_xor(p, 32);
        if (tid == 0) qbs[h] = p * 0.125f;
    }
}

// ---------------- K1: fused scores + softmax + ctxx ----------------
// 1024 threads (16 waves = 4/SIMD), one (b,t) per block, 8-row chunks,
// double-buffered LDS, register-staged prefetch. Low-VGPR design (~60 live):
// Phase A: wave w -> head w, reduce width 64 -> qw[16]/thread, l wholly in-wave.
// Phase C: thread = (head-quartet hq, f4-col c4) -> acc[4 x float4] = 16 regs.
__global__ __launch_bounds__(1024, 1) void k1_attn(const float* __restrict__ x,
                                                   const float* __restrict__ qwt,
                                                   const float* __restrict__ qbs,
                                                   float* __restrict__ ctxx) {
    __shared__ __align__(16) float xs[2][8][1024];   // 2 x 32 KB
    __shared__ __align__(16) float p_lds[8][16];
    __shared__ float l_lds[16];
    __shared__ float linv_lds[16];

    const int tid  = threadIdx.x;
    const int lane = tid & 63;
    const int w    = tid >> 6;          // wave 0..15 == head for phase A
    const int hq   = tid >> 8;          // 0..3 : heads hq*4..hq*4+3 in phase C
    const int c4   = tid & 255;         // float4 column in phase C
    const int bt   = blockIdx.x;
    const float* xb = x + (size_t)bt * 262144;

    // qw[4j+i] = qwt[(lane*4 + 256*j + i)*16 + w]   (16 VGPRs)
    float qw[16];
#pragma unroll
    for (int j = 0; j < 4; ++j)
#pragma unroll
        for (int i = 0; i < 4; ++i)
            qw[j * 4 + i] = qwt[((lane << 2) + (j << 8) + i) * 16 + w];
    const float qb = qbs[w];

    float4 acc[4];
#pragma unroll
    for (int i = 0; i < 4; ++i) acc[i] = make_float4(0.f, 0.f, 0.f, 0.f);
    float l_reg = 0.f;

    // prologue: chunk 0 (8 rows = 2048 float4) into registers, 2 f4/thread
    float4 st[2];
#pragma unroll
    for (int i = 0; i < 2; ++i)
        st[i] = *(const float4*)(xb + (size_t)(tid + i * 1024) * 4);

    for (int c = 0; c < 32; ++c) {
        const int cur = c & 1;
        float* xw = &xs[cur][0][0];
#pragma unroll
        for (int i = 0; i < 2; ++i)
            *(float4*)(xw + (size_t)(tid + i * 1024) * 4) = st[i];
        __syncthreads();                  // xs[cur] staged for all waves
        if (c < 31) {                     // prefetch next chunk during compute
            const float* nb = xb + (size_t)(c + 1) * 8192;
#pragma unroll
            for (int i = 0; i < 2; ++i)
                st[i] = *(const float4*)(nb + (size_t)(tid + i * 1024) * 4);
        }
        // ---- phase A: 8 rows, one head per wave, width-64 reduce ----
#pragma unroll
        for (int r = 0; r < 8; ++r) {
            const float* xr = &xs[cur][r][0];
            float4 a0 = *(const float4*)&xr[(lane << 2)];
            float4 a1 = *(const float4*)&xr[(lane << 2) + 256];
            float4 a2 = *(const float4*)&xr[(lane << 2) + 512];
            float4 a3 = *(const float4*)&xr[(lane << 2) + 768];
            float s0 = a0.x * qw[0]  + a0.y * qw[1]  + a0.z * qw[2]  + a0.w * qw[3]
                     + a1.x * qw[4]  + a1.y * qw[5]  + a1.z * qw[6]  + a1.w * qw[7];
            float s1 = a2.x * qw[8]  + a2.y * qw[9]  + a2.z * qw[10] + a2.w * qw[11]
                     + a3.x * qw[12] + a3.y * qw[13] + a3.z * qw[14] + a3.w * qw[15];
            float s = s0 + s1;
            s += __shfl_xor(s, 32); s += __shfl_xor(s, 16); s += __shfl_xor(s, 8);
            s += __shfl_xor(s, 4);  s += __shfl_xor(s, 2);  s += __shfl_xor(s, 1);
            if (lane == 0) {
                // scores ~|0.05| -> exp with shift 0 is numerically safe here
                float pv = __expf(s + qb);
                p_lds[r][w] = pv;
                l_reg += pv;
            }
        }
        __syncthreads();                  // p_lds ready
        // ---- phase C: thread = 1 float4 column x 4 heads, 8 rows ----
#pragma unroll
        for (int r = 0; r < 8; ++r) {
            float4 xv = *(const float4*)&xs[cur][r][c4 * 4];
            float4 p4 = *(const float4*)&p_lds[r][hq * 4];
            acc[0].x += p4.x * xv.x; acc[0].y += p4.x * xv.y; acc[0].z += p4.x * xv.z; acc[0].w += p4.x * xv.w;
            acc[1].x += p4.y * xv.x; acc[1].y += p4.y * xv.y; acc[1].z += p4.y * xv.z; acc[1].w += p4.y * xv.w;
            acc[2].x += p4.z * xv.x; acc[2].y += p4.z * xv.y; acc[2].z += p4.z * xv.z; acc[2].w += p4.z * xv.w;
            acc[3].x += p4.w * xv.x; acc[3].y += p4.w * xv.y; acc[3].z += p4.w * xv.z; acc[3].w += p4.w * xv.w;
        }
    }

    if (lane == 0) l_lds[w] = l_reg;
    __syncthreads();
    if (tid < 16) linv_lds[tid] = 1.0f / l_lds[tid];
    __syncthreads();
    float* ob = ctxx + (size_t)bt * 16384;
#pragma unroll
    for (int i = 0; i < 4; ++i) {
        float li = linv_lds[hq * 4 + i];
        float4 o = acc[i];
        o.x *= li; o.y *= li; o.z *= li; o.w *= li;
        *(float4*)(ob + (hq * 4 + i) * 1024 + c4 * 4) = o;
    }
}

// ---------------- K-split GEMM: outp[ks][r][e] = A_row(r)[koff:+512] . B[e, koff:+512] ----
// tile 16 rows x 64 cols, 256 threads, K-slice 512 (8 kc-steps of 64).
// FOLD=0: A_eff = A0
// FOLD=1: A_eff = A0 + A1 + biask (K-dim bias folded)
template<int FOLD>
__global__ __launch_bounds__(256, 2) void k_gemm2(const float* __restrict__ A0,
                                                  const float* __restrict__ A1,
                                                  const float* __restrict__ biask,
                                                  const float* __restrict__ Bw,
                                                  float* __restrict__ outp,
                                                  unsigned a_rstride, unsigned a_cstride,
                                                  unsigned ostride) {
    __shared__ __align__(16) float a_s[16][68];
    __shared__ __align__(16) float b_s[64][68];   // col-f4 swizzled: cs=(k4+e/4)&15
    const int tid = threadIdx.x;
    const int rc = blockIdx.x;     // row-chunk (16 rows)
    const int cb = blockIdx.y;     // col-block (64 cols)
    const int ks = blockIdx.z;     // K-split 0,1
    const int koff = ks * 512;
    const int rr = tid >> 4;       // output row 0..15
    const int ee = tid & 15;       // output cols ee*4..+3

    const size_t abase = (size_t)(rc * 16 + rr) * a_rstride + (size_t)cb * a_cstride + koff;

    float ac0 = 0.f, ac1 = 0.f, ac2 = 0.f, ac3 = 0.f;

    for (int kc = 0; kc < 8; ++kc) {
        __syncthreads();
        {   // stage A: 1 float4/thread
            float4 av = *(const float4*)(A0 + abase + kc * 64 + ee * 4);
            if (FOLD == 1) {
                float4 a1 = *(const float4*)(A1 + abase + kc * 64 + ee * 4);
                float4 bk4 = *(const float4*)(biask + koff + kc * 64 + ee * 4);
                av.x += a1.x + bk4.x; av.y += a1.y + bk4.y;
                av.z += a1.z + bk4.z; av.w += a1.w + bk4.w;
            }
            *(float4*)&a_s[rr][ee * 4] = av;
        }
        // stage B: 4 float4/thread, linear global -> swizzled LDS
#pragma unroll
        for (int i = 0; i < 4; ++i) {
            int f4i = tid + i * 256;
            int e = f4i >> 4, k4 = f4i & 15;
            float4 bv4 = *(const float4*)(Bw + (size_t)(cb * 64 + e) * 1024 + koff + kc * 64 + k4 * 4);
            int cs = (k4 + (e >> 2)) & 15;
            *(float4*)&b_s[e][cs * 4] = bv4;
        }
        __syncthreads();
#pragma unroll
        for (int k4 = 0; k4 < 16; ++k4) {
            float4 av = *(const float4*)&a_s[rr][k4 * 4];
            int cs = (k4 + ee) & 15;
            float4 b0 = *(const float4*)&b_s[ee * 4 + 0][cs * 4];
            float4 b1 = *(const float4*)&b_s[ee * 4 + 1][cs * 4];
            float4 b2 = *(const float4*)&b_s[ee * 4 + 2][cs * 4];
            float4 b3 = *(const float4*)&b_s[ee * 4 + 3][cs * 4];
            ac0 += av.x * b0.x + av.y * b0.y + av.z * b0.z + av.w * b0.w;
            ac1 += av.x * b1.x + av.y * b1.y + av.z * b1.z + av.w * b1.w;
            ac2 += av.x * b2.x + av.y * b2.y + av.z * b2.z + av.w * b2.w;
            ac3 += av.x * b3.x + av.y * b3.y + av.z * b3.z + av.w * b3.w;
        }
    }
    float4 o = make_float4(ac0, ac1, ac2, ac3);
    *(float4*)(outp + (size_t)ks * 256 * ostride + (size_t)(rc * 16 + rr) * ostride + cb * 64 + ee * 4) = o;
}

// ---------------- LayerNorm over D=1024, folds poolp0+poolp1+bo ----------------
__global__ __launch_bounds__(256) void k_ln(const float* __restrict__ poolp,
                                            const float* __restrict__ bo,
                                            const float* __restrict__ g,
                                            const float* __restrict__ bb,
                                            float* __restrict__ out) {
    __shared__ float sm[8];
    int row = blockIdx.x, tid = threadIdx.x;
    float4 v0 = *(const float4*)(poolp + (size_t)row * 1024 + tid * 4);
    float4 v1 = *(const float4*)(poolp + 262144u + (size_t)row * 1024 + tid * 4);
    float4 bv = *(const float4*)(bo + tid * 4);
    float4 v;
    v.x = v0.x + v1.x + bv.x; v.y = v0.y + v1.y + bv.y;
    v.z = v0.z + v1.z + bv.z; v.w = v0.w + v1.w + bv.w;
    float s = v.x + v.y + v.z + v.w;
    float q = v.x * v.x + v.y * v.y + v.z * v.z + v.w * v.w;
    s += __shfl_xor(s, 1);  q += __shfl_xor(q, 1);
    s += __shfl_xor(s, 2);  q += __shfl_xor(q, 2);
    s += __shfl_xor(s, 4);  q += __shfl_xor(q, 4);
    s += __shfl_xor(s, 8);  q += __shfl_xor(q, 8);
    s += __shfl_xor(s, 16); q += __shfl_xor(q, 16);
    s += __shfl_xor(s, 32); q += __shfl_xor(q, 32);
    if ((tid & 63) == 0) { sm[tid >> 6] = s; sm[4 + (tid >> 6)] = q; }
    __syncthreads();
    float S = sm[0] + sm[1] + sm[2] + sm[3];
    float Q = sm[4] + sm[5] + sm[6] + sm[7];
    float mu = S * (1.f / 1024.f);
    float var = Q * (1.f / 1024.f) - mu * mu;
    float rs = rsqrtf(var + 1e-6f);
    float4 gg = *(const float4*)(g + tid * 4);
    float4 be = *(const float4*)(bb + tid * 4);
    float4 o;
    o.x = (v.x - mu) * rs * gg.x + be.x;
    o.y = (v.y - mu) * rs * gg.y + be.y;
    o.z = (v.z - mu) * rs * gg.z + be.z;
    o.w = (v.w - mu) * rs * gg.w + be.w;
    *(float4*)(out + (size_t)row * 1024 + tid * 4) = o;
}

// ---------------- sim = (vt_hat . a_hat) * exp(ls) + lb ----------------
// folds vtp0+vtp1+pb; block: 32 vt rows x 64 audio rows; grid (32,8)
__global__ __launch_bounds__(256, 2) void k_sim(const float* __restrict__ vtp,
                                                const float* __restrict__ pb,
                                                const float* __restrict__ audio,
                                                const float* __restrict__ ls,
                                                const float* __restrict__ lb,
                                                float* __restrict__ out) {
    __shared__ float a_s[64][65];
    __shared__ float v_s[32][65];
    __shared__ float rinv_a[64];
    __shared__ float rinv_v[32];
    const int tid = threadIdx.x;
    const int lc = blockIdx.x;   // 0..31
    const int b  = blockIdx.y;   // 0..7
    const int al = tid >> 2, ak = (tid & 3) * 16;
    const int vl = tid >> 3, vk = (tid & 7) * 8;
    const int rg = tid >> 4, lg = tid & 15;
    float ssa = 0.f, ssv = 0.f;
    float c00=0,c01=0,c02=0,c03=0,c10=0,c11=0,c12=0,c13=0;

    for (int kc = 0; kc < 8; ++kc) {
        __syncthreads();
        {
            const float* ap = audio + (size_t)b * 1048576 + (size_t)(lc * 64 + al) * 512 + kc * 64 + ak;
#pragma unroll
            for (int i = 0; i < 4; ++i) {
                float4 wv4 = *(const float4*)(ap + i * 4);
                ssa += wv4.x * wv4.x + wv4.y * wv4.y + wv4.z * wv4.z + wv4.w * wv4.w;
                a_s[al][ak + i * 4 + 0] = wv4.x; a_s[al][ak + i * 4 + 1] = wv4.y;
                a_s[al][ak + i * 4 + 2] = wv4.z; a_s[al][ak + i * 4 + 3] = wv4.w;
            }
            const size_t voff = (size_t)(b * 32 + vl) * 512 + kc * 64 + vk;
#pragma unroll
            for (int i = 0; i < 2; ++i) {
                float4 p0 = *(const float4*)(vtp + voff + i * 4);
                float4 p1 = *(const float4*)(vtp + 131072u + voff + i * 4);
                float4 pbv = *(const float4*)(pb + kc * 64 + vk + i * 4);
                float4 wv4;
                wv4.x = p0.x + p1.x + pbv.x; wv4.y = p0.y + p1.y + pbv.y;
                wv4.z = p0.z + p1.z + pbv.z; wv4.w = p0.w + p1.w + pbv.w;
                ssv += wv4.x * wv4.x + wv4.y * wv4.y + wv4.z * wv4.z + wv4.w * wv4.w;
                v_s[vl][vk + i * 4 + 0] = wv4.x; v_s[vl][vk + i * 4 + 1] = wv4.y;
                v_s[vl][vk + i * 4 + 2] = wv4.z; v_s[vl][vk + i * 4 + 3] = wv4.w;
            }
        }
        __syncthreads();
#pragma unroll 2
        for (int k = 0; k < 64; ++k) {
            float v0 = v_s[rg * 2 + 0][k];
            float v1 = v_s[rg * 2 + 1][k];
            float x0 = a_s[lg * 4 + 0][k];
            float x1 = a_s[lg * 4 + 1][k];
            float x2 = a_s[lg * 4 + 2][k];
            float x3 = a_s[lg * 4 + 3][k];
            c00 += v0 * x0; c01 += v0 * x1; c02 += v0 * x2; c03 += v0 * x3;
            c10 += v1 * x0; c11 += v1 * x1; c12 += v1 * x2; c13 += v1 * x3;
        }
    }
    ssa += __shfl_xor(ssa, 1); ssa += __shfl_xor(ssa, 2);
    if ((tid & 3) == 0) rinv_a[al] = rsqrtf(ssa);
    ssv += __shfl_xor(ssv, 1); ssv += __shfl_xor(ssv, 2); ssv += __shfl_xor(ssv, 4);
    if ((tid & 7) == 0) rinv_v[vl] = rsqrtf(ssv);
    __syncthreads();
    const float sc = __expf(ls[0]);
    const float bias = lb[0];
    float ra0 = rinv_a[lg * 4 + 0], ra1 = rinv_a[lg * 4 + 1];
    float ra2 = rinv_a[lg * 4 + 2], ra3 = rinv_a[lg * 4 + 3];
    float accs[2][4] = {{c00,c01,c02,c03},{c10,c11,c12,c13}};
#pragma unroll
    for (int cr = 0; cr < 2; ++cr) {
        int t = rg * 2 + cr;
        float rv = rinv_v[t] * sc;
        float4 o;
        o.x = accs[cr][0] * rv * ra0 + bias;
        o.y = accs[cr][1] * rv * ra1 + bias;
        o.z = accs[cr][2] * rv * ra2 + bias;
        o.w = accs[cr][3] * rv * ra3 + bias;
        *(float4*)(out + (size_t)b * 65536 + (size_t)t * 2048 + lc * 64 + lg * 4) = o;
    }
}

// ---------------- launch ----------------
extern "C" void kernel_launch(void* const* d_in, const int* in_sizes, int n_in,
                              void* d_out, int out_size, void* d_ws, size_t ws_size,
                              hipStream_t stream) {
    (void)in_sizes; (void)n_in; (void)out_size;
    const float* video = (const float*)d_in[0];
    const float* audio = (const float*)d_in[1];
    const float* probe = (const float*)d_in[2];
    const float* wq    = (const float*)d_in[3];
    const float* wk    = (const float*)d_in[4];
    const float* wv    = (const float*)d_in[5];
    const float* bq    = (const float*)d_in[6];
    const float* bk    = (const float*)d_in[7];
    const float* bv    = (const float*)d_in[8];
    const float* wo    = (const float*)d_in[9];
    const float* bo    = (const float*)d_in[10];
    const float* lng   = (const float*)d_in[11];
    const float* lnb   = (const float*)d_in[12];
    const float* pw    = (const float*)d_in[13];
    const float* pb    = (const float*)d_in[14];
    const float* ls    = (const float*)d_in[15];
    const float* lb    = (const float*)d_in[16];
    float* ws  = (float*)d_ws;
    float* out = (float*)d_out;
    if (ws_size < FB_FLOATS * sizeof(float)) return;

    float* qwt  = ws + FB_QWT;
    float* qbs  = ws + FB_QB;
    float* qf   = ws + FB_QF;
    float* ctxx = ws + FB_CTXX;
    float* ctxp = ws + FB_CTXP;
    float* poolp= ws + FB_POOLP;
    float* lno  = ws + FB_LNO;
    float* vtp  = ws + FB_VTP;

    k_qflat<<<dim3(1024), dim3(256), 0, stream>>>(probe, wq, bq, qf);
    k_qwt<<<dim3(16, 16), dim3(64), 0, stream>>>(qf, wk, bk, qwt, qbs);
    k1_attn<<<dim3(256), dim3(1024), 0, stream>>>(video, qwt, qbs, ctxx);
    // G1: ctxx (head-block diagonal) @ wv^T -> ctxp   [K=1024 split 2]
    k_gemm2<0><<<dim3(16, 16, 2), dim3(256), 0, stream>>>(ctxx, nullptr, nullptr, wv, ctxp,
                                                          16384u, 1024u, 1024u);
    // G2: (ctxp0+ctxp1+bv) @ wo^T -> poolp            [K=1024 split 2]
    k_gemm2<1><<<dim3(16, 16, 2), dim3(256), 0, stream>>>(ctxp, ctxp + 262144u, bv, wo, poolp,
                                                          1024u, 0u, 1024u);
    k_ln<<<dim3(256), dim3(256), 0, stream>>>(poolp, bo, lng, lnb, lno);
    // G3: lno @ pw^T -> vtp                           [K=1024 split 2]
    k_gemm2<0><<<dim3(16, 8, 2), dim3(256), 0, stream>>>(lno, nullptr, nullptr, pw, vtp,
                                                         1024u, 0u, 512u);
    k_sim<<<dim3(32, 8), dim3(256), 0, stream>>>(vtp, pb, audio, ls, lb, out);
}